// Round 4
// baseline (3070.071 us; speedup 1.0000x reference)
//
#include <hip/hip_runtime.h>
#include <math.h>

#define BATCH  16384
#define TSTEPS 19
#define INW    17
#define HID    128
#define NROW   32          // batch rows per WG -> grid = 512 = 2 blocks/CU
#define THREADS 512        // 8 waves; wave wv owns j-tile wv (all 4 gates, both m-tiles)
#define KP     136         // padded row length (halfs) for h state (128+8)
#define KP0    40          // padded row length (halfs) for x (32+8)

typedef _Float16 f16x8 __attribute__((ext_vector_type(8)));
typedef float    f32x4 __attribute__((ext_vector_type(4)));

// ---- ws layout (halfs), MFMA-fragment-ordered tiles ----
#define W_BIG      0                 // 5 * 131072 = 655360
#define W_IH0      655360            // [512][32]: n_tile 0..31, tiles of 1024 (hi512|lo512)
#define W_HEAD     688128            // [32 rows][128]: (n_tile 0..1, ks 0..3) tiles of 1024
#define WS_HALFS   696320

__device__ __forceinline__ float fast_rcp(float x) { return __builtin_amdgcn_rcpf(x); }
__device__ __forceinline__ float sigm(float z)  { return fast_rcp(1.0f + __expf(-z)); }
__device__ __forceinline__ float tanh_(float z) { return 1.0f - 2.0f * fast_rcp(1.0f + __expf(2.0f * z)); }

// ---------------- weight conversion: fp32 -> f16 hi/lo, fragment order ----------------
__global__ void convert_w(const float* __restrict__ Whh0, const float* __restrict__ Whh1,
                          const float* __restrict__ Whh2, const float* __restrict__ Wih1,
                          const float* __restrict__ Wih2, const float* __restrict__ Wih0,
                          const float* __restrict__ Wl, _Float16* __restrict__ ws)
{
    int idx = blockIdx.x * 256 + threadIdx.x;
    if (idx < 327680) {
        int m = idx >> 16, e = idx & 65535;
        int r = e >> 7, k = e & 127;
        const float* src = (m == 0) ? Whh0 : (m == 1) ? Whh1 : (m == 2) ? Whh2
                          : (m == 3) ? Wih1 : Wih2;
        float v = src[e];
        _Float16 hi = (_Float16)v;
        int n_tile = r >> 4, colr = r & 15, ks = k >> 5, qd = (k >> 3) & 3, j = k & 7;
        int dst = W_BIG + m * 131072 + (n_tile * 4 + ks) * 1024 + (qd * 16 + colr) * 8 + j;
        ws[dst]       = hi;
        ws[dst + 512] = (_Float16)(v - (float)hi);
    } else if (idx < 344064) {
        int e = idx - 327680;              // [0, 16384)
        int r = e >> 5, k = e & 31;
        float v = (k < INW) ? Wih0[r * INW + k] : 0.0f;
        _Float16 hi = (_Float16)v;
        int n_tile = r >> 4, colr = r & 15, qd = k >> 3, j = k & 7;
        int dst = W_IH0 + n_tile * 1024 + (qd * 16 + colr) * 8 + j;
        ws[dst]       = hi;
        ws[dst + 512] = (_Float16)(v - (float)hi);
    } else if (idx < 348160) {
        int e = idx - 344064;              // [0, 4096)
        int r = e >> 7, k = e & 127;
        float v = (r < INW) ? Wl[(size_t)r * HID + k] : 0.0f;
        _Float16 hi = (_Float16)v;
        int n_tile = r >> 4, colr = r & 15, ks = k >> 5, qd = (k >> 3) & 3, j = k & 7;
        int dst = W_HEAD + (n_tile * 4 + ks) * 1024 + (qd * 16 + colr) * 8 + j;
        ws[dst]       = hi;
        ws[dst + 512] = (_Float16)(v - (float)hi);
    }
}

// ---------------- GEMM helpers (software-pipelined, sched_barrier-fenced) ----------------
// acc[mt][g]: rows m = mt*16 + quad*4 + r, cols n = g*128 + wv*16 + col
// A from LDS h planes (hi/lo, row-major stride KP); B fragment tiles (coalesced lane*8).
// Pipeline: B tiles double-buffered, issued 2 regions ahead; A frags double-buffered per ks.
__device__ __forceinline__ void gemm_h(f32x4 acc[2][4],
                                       const _Float16* __restrict__ Ahi,
                                       const _Float16* __restrict__ Alo,
                                       const _Float16* __restrict__ B,
                                       int col, int q8, int wv, int lane)
{
    const _Float16* a_h = Ahi + col * KP;
    const _Float16* a_l = Alo + col * KP;
    const int l8 = lane * 8;
    const _Float16* Bw = B + (wv * 4) * 1024 + l8;   // tile (ks,g) at Bw + (g*32+ks)*1024

    f16x8 bh[2], bl[2];
    f16x8 ah0[2], al0[2], ah1[2], al1[2];

    // prologue: A frags for ks=0; B tiles for regions 0,1
    ah0[0] = *(const f16x8*)(a_h + q8);
    al0[0] = *(const f16x8*)(a_l + q8);
    ah1[0] = *(const f16x8*)(a_h + 16 * KP + q8);
    al1[0] = *(const f16x8*)(a_l + 16 * KP + q8);
    bh[0] = *(const f16x8*)(Bw);
    bl[0] = *(const f16x8*)(Bw + 512);
    bh[1] = *(const f16x8*)(Bw + 32 * 1024);
    bl[1] = *(const f16x8*)(Bw + 32 * 1024 + 512);
    __builtin_amdgcn_sched_barrier(0);

#pragma unroll
    for (int it = 0; it < 16; ++it) {
        const int ks = it >> 2, g = it & 3;
        const int sl = it & 1;      // B slot
        const int ka = ks & 1;      // A slot
        __builtin_amdgcn_s_setprio(1);
        acc[0][g] = __builtin_amdgcn_mfma_f32_16x16x32_f16(ah0[ka], bh[sl], acc[0][g], 0, 0, 0);
        acc[0][g] = __builtin_amdgcn_mfma_f32_16x16x32_f16(al0[ka], bh[sl], acc[0][g], 0, 0, 0);
        acc[0][g] = __builtin_amdgcn_mfma_f32_16x16x32_f16(ah0[ka], bl[sl], acc[0][g], 0, 0, 0);
        acc[1][g] = __builtin_amdgcn_mfma_f32_16x16x32_f16(ah1[ka], bh[sl], acc[1][g], 0, 0, 0);
        acc[1][g] = __builtin_amdgcn_mfma_f32_16x16x32_f16(al1[ka], bh[sl], acc[1][g], 0, 0, 0);
        acc[1][g] = __builtin_amdgcn_mfma_f32_16x16x32_f16(ah1[ka], bl[sl], acc[1][g], 0, 0, 0);
        __builtin_amdgcn_s_setprio(0);
        // issue B loads for region it+2 (consumed 2 regions later)
        if (it < 14) {
            const int it2 = it + 2;
            const _Float16* p = Bw + (((it2) & 3) * 32 + ((it2) >> 2)) * 1024;
            bh[sl] = *(const f16x8*)(p);
            bl[sl] = *(const f16x8*)(p + 512);
        }
        // issue A frag loads for ks+1 early in each ks (consumed 4 regions later)
        if (g == 0 && ks < 3) {
            const int ko = (ks + 1) * 32 + q8;
            ah0[ka ^ 1] = *(const f16x8*)(a_h + ko);
            al0[ka ^ 1] = *(const f16x8*)(a_l + ko);
            ah1[ka ^ 1] = *(const f16x8*)(a_h + 16 * KP + ko);
            al1[ka ^ 1] = *(const f16x8*)(a_l + 16 * KP + ko);
        }
        __builtin_amdgcn_sched_barrier(0);   // pin the pipeline: nothing crosses
    }
}

// x-part for layer 0: K=32 (padded), 4 regions, same depth-2 B pipeline
__device__ __forceinline__ void gemm_x(f32x4 acc[2][4],
                                       const _Float16* __restrict__ Xhi,
                                       const _Float16* __restrict__ Xlo,
                                       const _Float16* __restrict__ B,
                                       int col, int q8, int wv, int lane)
{
    const int l8 = lane * 8;
    const _Float16* Bw = B + wv * 1024 + l8;         // tile g at Bw + g*8*1024
    f16x8 ah0 = *(const f16x8*)(Xhi + col * KP0 + q8);
    f16x8 al0 = *(const f16x8*)(Xlo + col * KP0 + q8);
    f16x8 ah1 = *(const f16x8*)(Xhi + (16 + col) * KP0 + q8);
    f16x8 al1 = *(const f16x8*)(Xlo + (16 + col) * KP0 + q8);
    f16x8 bh[2], bl[2];
    bh[0] = *(const f16x8*)(Bw);
    bl[0] = *(const f16x8*)(Bw + 512);
    bh[1] = *(const f16x8*)(Bw + 8 * 1024);
    bl[1] = *(const f16x8*)(Bw + 8 * 1024 + 512);
    __builtin_amdgcn_sched_barrier(0);
#pragma unroll
    for (int g = 0; g < 4; ++g) {
        const int sl = g & 1;
        __builtin_amdgcn_s_setprio(1);
        acc[0][g] = __builtin_amdgcn_mfma_f32_16x16x32_f16(ah0, bh[sl], acc[0][g], 0, 0, 0);
        acc[0][g] = __builtin_amdgcn_mfma_f32_16x16x32_f16(al0, bh[sl], acc[0][g], 0, 0, 0);
        acc[0][g] = __builtin_amdgcn_mfma_f32_16x16x32_f16(ah0, bl[sl], acc[0][g], 0, 0, 0);
        acc[1][g] = __builtin_amdgcn_mfma_f32_16x16x32_f16(ah1, bh[sl], acc[1][g], 0, 0, 0);
        acc[1][g] = __builtin_amdgcn_mfma_f32_16x16x32_f16(al1, bh[sl], acc[1][g], 0, 0, 0);
        acc[1][g] = __builtin_amdgcn_mfma_f32_16x16x32_f16(ah1, bl[sl], acc[1][g], 0, 0, 0);
        __builtin_amdgcn_s_setprio(0);
        if (g < 2) {
            const _Float16* p = Bw + (g + 2) * 8 * 1024;
            bh[sl] = *(const f16x8*)(p);
            bl[sl] = *(const f16x8*)(p + 512);
        }
        __builtin_amdgcn_sched_barrier(0);
    }
}

// gates + h write for one layer (acc consumed, cst updated, h hi/lo -> LDS)
__device__ __forceinline__ void gates_store(f32x4 acc[2][4], f32x4 cst[2],
                                            _Float16* __restrict__ HsHi,
                                            _Float16* __restrict__ HsLo,
                                            int quad, int col, int wv)
{
#pragma unroll
    for (int mt = 0; mt < 2; ++mt) {
#pragma unroll
        for (int r = 0; r < 4; ++r) {
            float zi = acc[mt][0][r];
            float zf = acc[mt][1][r];
            float zg = acc[mt][2][r];
            float zo = acc[mt][3][r];
            float ig = sigm(zi), fg = sigm(zf), og = sigm(zo), gg = tanh_(zg);
            float cn = fg * cst[mt][r] + ig * gg;
            cst[mt][r] = cn;
            float h = og * tanh_(cn);
            int m = mt * 16 + quad * 4 + r;
            int j = wv * 16 + col;
            _Float16 hh = (_Float16)h;
            HsHi[m * KP + j] = hh;
            HsLo[m * KP + j] = (_Float16)(h - (float)hh);
        }
    }
}

// out[:, t, :] = h2 @ Wl^T + bl (waves 0..3 only: mt = wv>>1, nt = wv&1)
__device__ __forceinline__ void head_out(const _Float16* __restrict__ wsp,
                                         const _Float16* __restrict__ HsHi2,
                                         const _Float16* __restrict__ HsLo2,
                                         float* __restrict__ out, int b0, int t,
                                         int wv, int lane, int col, int quad, int q8,
                                         float blv)
{
    const int mt = wv >> 1, nt = wv & 1;
    const _Float16* ah = HsHi2 + (mt * 16 + col) * KP;
    const _Float16* al = HsLo2 + (mt * 16 + col) * KP;
    f32x4 o = (f32x4){0, 0, 0, 0};
#pragma unroll
    for (int ks = 0; ks < 4; ++ks) {
        const _Float16* bt = wsp + W_HEAD + (nt * 4 + ks) * 1024 + lane * 8;
        f16x8 a_h = *(const f16x8*)(ah + ks * 32 + q8);
        f16x8 a_l = *(const f16x8*)(al + ks * 32 + q8);
        f16x8 b_h = *(const f16x8*)(bt);
        f16x8 b_l = *(const f16x8*)(bt + 512);
        o = __builtin_amdgcn_mfma_f32_16x16x32_f16(a_h, b_h, o, 0, 0, 0);
        o = __builtin_amdgcn_mfma_f32_16x16x32_f16(a_l, b_h, o, 0, 0, 0);
        o = __builtin_amdgcn_mfma_f32_16x16x32_f16(a_h, b_l, o, 0, 0, 0);
    }
    int i = nt * 16 + col;
    if (i < INW) {
#pragma unroll
        for (int r = 0; r < 4; ++r) {
            int m = mt * 16 + quad * 4 + r;
            out[(size_t)(b0 + m) * (TSTEPS * INW) + t * INW + i] = o[r] + blv;
        }
    }
}

// ---------------- main kernel ----------------
// Restructured phases per timestep (only Wih(l)*h_new(l-1) depends on this step's gates):
//   P1: head(t-1) + accA = b0 + Wih0*x[t] + Whh0*h0 ; accB = b1 + Whh1*h1_old
//   g0 -> h0_new
//   P2: stage x[t+1] (split load/write) ; accA = b2 + Whh2*h2_old ; accB += Wih1*h0_new
//   g1 -> h1_new
//   P3: accA += Wih2*h1_new
//   g2 -> h2_new
__global__ __launch_bounds__(THREADS, 2) void lstm_mfma(
    const float* __restrict__ x,
    const float* __restrict__ bih0, const float* __restrict__ bhh0,
    const float* __restrict__ bih1, const float* __restrict__ bhh1,
    const float* __restrict__ bih2, const float* __restrict__ bhh2,
    const float* __restrict__ bl,
    const _Float16* __restrict__ wsp,
    float* __restrict__ out)
{
    __shared__ _Float16 Hs[2][3][NROW][KP];    // [hi/lo][layer][m][k]  = 52224 B
    __shared__ _Float16 Xs[2][2][NROW][KP0];   // [buf][hi/lo][m][k]    = 10240 B
    __shared__ float    Bs[3][512];            // bih+bhh per layer     = 6144 B

    const int tid  = threadIdx.x;
    const int wv   = tid >> 6;
    const int lane = tid & 63;
    const int col  = lane & 15;
    const int quad = lane >> 4;
    const int q8   = quad * 8;
    const int b0   = blockIdx.x * NROW;

    // stage bias sums into LDS (saves persistent registers)
    for (int i = tid; i < 1536; i += THREADS) {
        int l = i >> 9, n = i & 511;
        const float* bi = (l == 0) ? bih0 : (l == 1) ? bih1 : bih2;
        const float* bh = (l == 0) ? bhh0 : (l == 1) ? bhh1 : bhh2;
        Bs[l][n] = bi[n] + bh[n];
    }
    // zero h state (hi+lo planes): 52224 B = 13056 floats
    for (int i = tid; i < 13056; i += THREADS) ((float*)Hs)[i] = 0.0f;

    // stage x[:, 0, :] as f16 hi/lo into buffer 0 (K padded to 32)
    for (int ii = tid; ii < NROW * 32; ii += THREADS) {
        int m = ii >> 5, k = ii & 31;
        float v = (k < INW) ? x[(size_t)(b0 + m) * (TSTEPS * INW) + k] : 0.0f;
        _Float16 hi = (_Float16)v;
        Xs[0][0][m][k] = hi;
        Xs[0][1][m][k] = (_Float16)(v - (float)hi);
    }

    f32x4 cst[3][2];
#pragma unroll
    for (int l = 0; l < 3; ++l) { cst[l][0] = (f32x4){0,0,0,0}; cst[l][1] = (f32x4){0,0,0,0}; }

    // weight pointers (fragment-ordered)
    const _Float16* Whh[3] = {wsp + W_BIG,  wsp + W_BIG + 131072, wsp + W_BIG + 262144};
    const _Float16* Wih[3] = {wsp + W_IH0, wsp + W_BIG + 393216, wsp + W_BIG + 524288};

    // head bias (waves 0..3 only)
    float blv = 0.0f;
    {
        int i = (wv & 1) * 16 + col;
        if (wv < 4 && i < INW) blv = bl[i];
    }

    __syncthreads();

    int tb = 0;
#pragma unroll 1
    for (int t = 0; t < TSTEPS; ++t) {
        f32x4 accA[2][4], accB[2][4];

        // ---- phase 1: head(t-1) folded in; L0 full; L1 recurrent ----
        if (t > 0 && wv < 4)
            head_out(wsp, &Hs[0][2][0][0], &Hs[1][2][0][0], out, b0, t - 1,
                     wv, lane, col, quad, q8, blv);
#pragma unroll
        for (int mt = 0; mt < 2; ++mt)
#pragma unroll
            for (int g = 0; g < 4; ++g) {
                float bvA = Bs[0][g * 128 + wv * 16 + col];
                float bvB = Bs[1][g * 128 + wv * 16 + col];
                accA[mt][g] = (f32x4){bvA, bvA, bvA, bvA};
                accB[mt][g] = (f32x4){bvB, bvB, bvB, bvB};
            }
        gemm_x(accA, &Xs[tb][0][0][0], &Xs[tb][1][0][0], Wih[0], col, q8, wv, lane);
        gemm_h(accA, &Hs[0][0][0][0], &Hs[1][0][0][0], Whh[0], col, q8, wv, lane);
        gemm_h(accB, &Hs[0][1][0][0], &Hs[1][1][0][0], Whh[1], col, q8, wv, lane);

        __syncthreads();   // all reads of Hs[0] complete
        gates_store(accA, cst[0], &Hs[0][0][0][0], &Hs[1][0][0][0], quad, col, wv);
        __syncthreads();   // h0_new visible

        // ---- phase 2: x[t+1] load-early/write-late; L2 recurrent; L1 input ----
        const int nb = tb ^ 1;
        const int t2 = t + 1;
        float xva[2];
        if (t2 < TSTEPS) {
#pragma unroll
            for (int u = 0; u < 2; ++u) {
                int ii = tid + u * THREADS;
                int m = ii >> 5, k = ii & 31;
                xva[u] = (k < INW) ? x[(size_t)(b0 + m) * (TSTEPS * INW) + t2 * INW + k] : 0.0f;
            }
        }
#pragma unroll
        for (int mt = 0; mt < 2; ++mt)
#pragma unroll
            for (int g = 0; g < 4; ++g) {
                float bvA = Bs[2][g * 128 + wv * 16 + col];
                accA[mt][g] = (f32x4){bvA, bvA, bvA, bvA};
            }
        gemm_h(accA, &Hs[0][2][0][0], &Hs[1][2][0][0], Whh[2], col, q8, wv, lane);
        gemm_h(accB, &Hs[0][0][0][0], &Hs[1][0][0][0], Wih[1], col, q8, wv, lane);
        if (t2 < TSTEPS) {
#pragma unroll
            for (int u = 0; u < 2; ++u) {
                int ii = tid + u * THREADS;
                int m = ii >> 5, k = ii & 31;
                _Float16 hi = (_Float16)xva[u];
                Xs[nb][0][m][k] = hi;
                Xs[nb][1][m][k] = (_Float16)(xva[u] - (float)hi);
            }
        }

        __syncthreads();   // reads of Hs[2] (Whh2) and Hs[0] (Wih1) complete
        gates_store(accB, cst[1], &Hs[0][1][0][0], &Hs[1][1][0][0], quad, col, wv);
        __syncthreads();   // h1_new visible

        // ---- phase 3: L2 input ----
        gemm_h(accA, &Hs[0][1][0][0], &Hs[1][1][0][0], Wih[2], col, q8, wv, lane);

        __syncthreads();   // reads of Hs[1] complete
        gates_store(accA, cst[2], &Hs[0][2][0][0], &Hs[1][2][0][0], quad, col, wv);
        __syncthreads();   // h2_new visible (head reads it next iteration / epilogue)

        tb = nb;
    }

    // epilogue head for t = TSTEPS-1
    if (wv < 4)
        head_out(wsp, &Hs[0][2][0][0], &Hs[1][2][0][0], out, b0, TSTEPS - 1,
                 wv, lane, col, quad, q8, blv);
}

extern "C" void kernel_launch(void* const* d_in, const int* in_sizes, int n_in,
                              void* d_out, int out_size, void* d_ws, size_t ws_size,
                              hipStream_t stream) {
    const float* x    = (const float*)d_in[0];
    const float* Wih0 = (const float*)d_in[1];
    const float* Whh0 = (const float*)d_in[2];
    const float* bih0 = (const float*)d_in[3];
    const float* bhh0 = (const float*)d_in[4];
    const float* Wih1 = (const float*)d_in[5];
    const float* Whh1 = (const float*)d_in[6];
    const float* bih1 = (const float*)d_in[7];
    const float* bhh1 = (const float*)d_in[8];
    const float* Wih2 = (const float*)d_in[9];
    const float* Whh2 = (const float*)d_in[10];
    const float* bih2 = (const float*)d_in[11];
    const float* bhh2 = (const float*)d_in[12];
    const float* Wl   = (const float*)d_in[13];
    const float* bl   = (const float*)d_in[14];
    float* out = (float*)d_out;
    _Float16* ws = (_Float16*)d_ws;

    convert_w<<<(348160 + 255) / 256, 256, 0, stream>>>(Whh0, Whh1, Whh2, Wih1, Wih2, Wih0, Wl, ws);
    lstm_mfma<<<BATCH / NROW, THREADS, 0, stream>>>(
        x, bih0, bhh0, bih1, bhh1, bih2, bhh2, bl, ws, out);
}

// Round 5
// 2786.705 us; speedup vs baseline: 1.1017x; 1.1017x over previous
//
#include <hip/hip_runtime.h>
#include <math.h>

#define BATCH  16384
#define TSTEPS 19
#define INW    17
#define HID    128
#define NROW   32          // batch rows per WG -> grid = 512 = 2 blocks/CU
#define THREADS 512        // 8 waves; wave wv owns j-tile wv (all 4 gates, both m-tiles)
#define KP     136         // padded row length (halfs) for h state (128+8)
#define KP0    40          // padded row length (halfs) for x (32+8)

typedef _Float16 f16x8 __attribute__((ext_vector_type(8)));
typedef float    f32x4 __attribute__((ext_vector_type(4)));

// ---- ws layout (halfs), MFMA-fragment-ordered tiles ----
#define W_BIG      0                 // 5 * 131072 = 655360
#define W_IH0      655360            // [512][32]: n_tile 0..31, tiles of 1024 (hi512|lo512)
#define W_HEAD     688128            // [32 rows][128]: (n_tile 0..1, ks 0..3) tiles of 1024
#define WS_HALFS   696320

__device__ __forceinline__ float fast_rcp(float x) { return __builtin_amdgcn_rcpf(x); }
__device__ __forceinline__ float sigm(float z)  { return fast_rcp(1.0f + __expf(-z)); }
__device__ __forceinline__ float tanh_(float z) { return 1.0f - 2.0f * fast_rcp(1.0f + __expf(2.0f * z)); }

// ---------------- weight conversion: fp32 -> f16 hi/lo, fragment order ----------------
__global__ void convert_w(const float* __restrict__ Whh0, const float* __restrict__ Whh1,
                          const float* __restrict__ Whh2, const float* __restrict__ Wih1,
                          const float* __restrict__ Wih2, const float* __restrict__ Wih0,
                          const float* __restrict__ Wl, _Float16* __restrict__ ws)
{
    int idx = blockIdx.x * 256 + threadIdx.x;
    if (idx < 327680) {
        int m = idx >> 16, e = idx & 65535;
        int r = e >> 7, k = e & 127;
        const float* src = (m == 0) ? Whh0 : (m == 1) ? Whh1 : (m == 2) ? Whh2
                          : (m == 3) ? Wih1 : Wih2;
        float v = src[e];
        _Float16 hi = (_Float16)v;
        int n_tile = r >> 4, colr = r & 15, ks = k >> 5, qd = (k >> 3) & 3, j = k & 7;
        int dst = W_BIG + m * 131072 + (n_tile * 4 + ks) * 1024 + (qd * 16 + colr) * 8 + j;
        ws[dst]       = hi;
        ws[dst + 512] = (_Float16)(v - (float)hi);
    } else if (idx < 344064) {
        int e = idx - 327680;              // [0, 16384)
        int r = e >> 5, k = e & 31;
        float v = (k < INW) ? Wih0[r * INW + k] : 0.0f;
        _Float16 hi = (_Float16)v;
        int n_tile = r >> 4, colr = r & 15, qd = k >> 3, j = k & 7;
        int dst = W_IH0 + n_tile * 1024 + (qd * 16 + colr) * 8 + j;
        ws[dst]       = hi;
        ws[dst + 512] = (_Float16)(v - (float)hi);
    } else if (idx < 348160) {
        int e = idx - 344064;              // [0, 4096)
        int r = e >> 7, k = e & 127;
        float v = (r < INW) ? Wl[(size_t)r * HID + k] : 0.0f;
        _Float16 hi = (_Float16)v;
        int n_tile = r >> 4, colr = r & 15, ks = k >> 5, qd = (k >> 3) & 3, j = k & 7;
        int dst = W_HEAD + (n_tile * 4 + ks) * 1024 + (qd * 16 + colr) * 8 + j;
        ws[dst]       = hi;
        ws[dst + 512] = (_Float16)(v - (float)hi);
    }
}

// ---------------- GEMM helpers (software-pipelined, sched_barrier-fenced) ----------------
// acc[mt][g]: rows m = mt*16 + quad*4 + r, cols n = g*128 + wv*16 + col
// A from LDS h planes (hi/lo, row-major stride KP); B fragment tiles (coalesced lane*8).
// Pipeline: B tiles double-buffered, issued 2 regions ahead; A frags double-buffered per ks.
__device__ __forceinline__ void gemm_h(f32x4 acc[2][4],
                                       const _Float16* __restrict__ Ahi,
                                       const _Float16* __restrict__ Alo,
                                       const _Float16* __restrict__ B,
                                       int col, int q8, int wv, int lane)
{
    const _Float16* a_h = Ahi + col * KP;
    const _Float16* a_l = Alo + col * KP;
    const int l8 = lane * 8;
    const _Float16* Bw = B + (wv * 4) * 1024 + l8;   // tile (ks,g) at Bw + (g*32+ks)*1024

    f16x8 bh[2], bl[2];
    f16x8 ah0[2], al0[2], ah1[2], al1[2];

    // prologue: A frags for ks=0; B tiles for regions 0,1
    ah0[0] = *(const f16x8*)(a_h + q8);
    al0[0] = *(const f16x8*)(a_l + q8);
    ah1[0] = *(const f16x8*)(a_h + 16 * KP + q8);
    al1[0] = *(const f16x8*)(a_l + 16 * KP + q8);
    bh[0] = *(const f16x8*)(Bw);
    bl[0] = *(const f16x8*)(Bw + 512);
    bh[1] = *(const f16x8*)(Bw + 32 * 1024);
    bl[1] = *(const f16x8*)(Bw + 32 * 1024 + 512);
    __builtin_amdgcn_sched_barrier(0);

#pragma unroll
    for (int it = 0; it < 16; ++it) {
        const int ks = it >> 2, g = it & 3;
        const int sl = it & 1;      // B slot
        const int ka = ks & 1;      // A slot
        __builtin_amdgcn_s_setprio(1);
        acc[0][g] = __builtin_amdgcn_mfma_f32_16x16x32_f16(ah0[ka], bh[sl], acc[0][g], 0, 0, 0);
        acc[0][g] = __builtin_amdgcn_mfma_f32_16x16x32_f16(al0[ka], bh[sl], acc[0][g], 0, 0, 0);
        acc[0][g] = __builtin_amdgcn_mfma_f32_16x16x32_f16(ah0[ka], bl[sl], acc[0][g], 0, 0, 0);
        acc[1][g] = __builtin_amdgcn_mfma_f32_16x16x32_f16(ah1[ka], bh[sl], acc[1][g], 0, 0, 0);
        acc[1][g] = __builtin_amdgcn_mfma_f32_16x16x32_f16(al1[ka], bh[sl], acc[1][g], 0, 0, 0);
        acc[1][g] = __builtin_amdgcn_mfma_f32_16x16x32_f16(ah1[ka], bl[sl], acc[1][g], 0, 0, 0);
        __builtin_amdgcn_s_setprio(0);
        // issue B loads for region it+2 (consumed 2 regions later)
        if (it < 14) {
            const int it2 = it + 2;
            const _Float16* p = Bw + (((it2) & 3) * 32 + ((it2) >> 2)) * 1024;
            bh[sl] = *(const f16x8*)(p);
            bl[sl] = *(const f16x8*)(p + 512);
        }
        // issue A frag loads for ks+1 early in each ks (consumed 4 regions later)
        if (g == 0 && ks < 3) {
            const int ko = (ks + 1) * 32 + q8;
            ah0[ka ^ 1] = *(const f16x8*)(a_h + ko);
            al0[ka ^ 1] = *(const f16x8*)(a_l + ko);
            ah1[ka ^ 1] = *(const f16x8*)(a_h + 16 * KP + ko);
            al1[ka ^ 1] = *(const f16x8*)(a_l + 16 * KP + ko);
        }
        __builtin_amdgcn_sched_barrier(0);   // pin the pipeline: nothing crosses
    }
}

// x-part for layer 0: K=32 (padded), 4 regions, same depth-2 B pipeline
__device__ __forceinline__ void gemm_x(f32x4 acc[2][4],
                                       const _Float16* __restrict__ Xhi,
                                       const _Float16* __restrict__ Xlo,
                                       const _Float16* __restrict__ B,
                                       int col, int q8, int wv, int lane)
{
    const int l8 = lane * 8;
    const _Float16* Bw = B + wv * 1024 + l8;         // tile g at Bw + g*8*1024
    f16x8 ah0 = *(const f16x8*)(Xhi + col * KP0 + q8);
    f16x8 al0 = *(const f16x8*)(Xlo + col * KP0 + q8);
    f16x8 ah1 = *(const f16x8*)(Xhi + (16 + col) * KP0 + q8);
    f16x8 al1 = *(const f16x8*)(Xlo + (16 + col) * KP0 + q8);
    f16x8 bh[2], bl[2];
    bh[0] = *(const f16x8*)(Bw);
    bl[0] = *(const f16x8*)(Bw + 512);
    bh[1] = *(const f16x8*)(Bw + 8 * 1024);
    bl[1] = *(const f16x8*)(Bw + 8 * 1024 + 512);
    __builtin_amdgcn_sched_barrier(0);
#pragma unroll
    for (int g = 0; g < 4; ++g) {
        const int sl = g & 1;
        __builtin_amdgcn_s_setprio(1);
        acc[0][g] = __builtin_amdgcn_mfma_f32_16x16x32_f16(ah0, bh[sl], acc[0][g], 0, 0, 0);
        acc[0][g] = __builtin_amdgcn_mfma_f32_16x16x32_f16(al0, bh[sl], acc[0][g], 0, 0, 0);
        acc[0][g] = __builtin_amdgcn_mfma_f32_16x16x32_f16(ah0, bl[sl], acc[0][g], 0, 0, 0);
        acc[1][g] = __builtin_amdgcn_mfma_f32_16x16x32_f16(ah1, bh[sl], acc[1][g], 0, 0, 0);
        acc[1][g] = __builtin_amdgcn_mfma_f32_16x16x32_f16(al1, bh[sl], acc[1][g], 0, 0, 0);
        acc[1][g] = __builtin_amdgcn_mfma_f32_16x16x32_f16(ah1, bl[sl], acc[1][g], 0, 0, 0);
        __builtin_amdgcn_s_setprio(0);
        if (g < 2) {
            const _Float16* p = Bw + (g + 2) * 8 * 1024;
            bh[sl] = *(const f16x8*)(p);
            bl[sl] = *(const f16x8*)(p + 512);
        }
        __builtin_amdgcn_sched_barrier(0);
    }
}

// gates + h write for one layer (acc consumed, cst updated, h hi/lo -> LDS)
__device__ __forceinline__ void gates_store(f32x4 acc[2][4], f32x4 cst[2],
                                            _Float16* __restrict__ HsHi,
                                            _Float16* __restrict__ HsLo,
                                            int quad, int col, int wv)
{
#pragma unroll
    for (int mt = 0; mt < 2; ++mt) {
#pragma unroll
        for (int r = 0; r < 4; ++r) {
            float zi = acc[mt][0][r];
            float zf = acc[mt][1][r];
            float zg = acc[mt][2][r];
            float zo = acc[mt][3][r];
            float ig = sigm(zi), fg = sigm(zf), og = sigm(zo), gg = tanh_(zg);
            float cn = fg * cst[mt][r] + ig * gg;
            cst[mt][r] = cn;
            float h = og * tanh_(cn);
            int m = mt * 16 + quad * 4 + r;
            int j = wv * 16 + col;
            _Float16 hh = (_Float16)h;
            HsHi[m * KP + j] = hh;
            HsLo[m * KP + j] = (_Float16)(h - (float)hh);
        }
    }
}

// out[:, t, :] = h2 @ Wl^T + bl (waves 0..3 only: mt = wv>>1, nt = wv&1)
__device__ __forceinline__ void head_out(const _Float16* __restrict__ wsp,
                                         const _Float16* __restrict__ HsHi2,
                                         const _Float16* __restrict__ HsLo2,
                                         float* __restrict__ out, int b0, int t,
                                         int wv, int lane, int col, int quad, int q8,
                                         float blv)
{
    const int mt = wv >> 1, nt = wv & 1;
    const _Float16* ah = HsHi2 + (mt * 16 + col) * KP;
    const _Float16* al = HsLo2 + (mt * 16 + col) * KP;
    f32x4 o = (f32x4){0, 0, 0, 0};
#pragma unroll
    for (int ks = 0; ks < 4; ++ks) {
        const _Float16* bt = wsp + W_HEAD + (nt * 4 + ks) * 1024 + lane * 8;
        f16x8 a_h = *(const f16x8*)(ah + ks * 32 + q8);
        f16x8 a_l = *(const f16x8*)(al + ks * 32 + q8);
        f16x8 b_h = *(const f16x8*)(bt);
        f16x8 b_l = *(const f16x8*)(bt + 512);
        o = __builtin_amdgcn_mfma_f32_16x16x32_f16(a_h, b_h, o, 0, 0, 0);
        o = __builtin_amdgcn_mfma_f32_16x16x32_f16(a_l, b_h, o, 0, 0, 0);
        o = __builtin_amdgcn_mfma_f32_16x16x32_f16(a_h, b_l, o, 0, 0, 0);
    }
    int i = nt * 16 + col;
    if (i < INW) {
#pragma unroll
        for (int r = 0; r < 4; ++r) {
            int m = mt * 16 + quad * 4 + r;
            out[(size_t)(b0 + m) * (TSTEPS * INW) + t * INW + i] = o[r] + blv;
        }
    }
}

// ---------------- main kernel ----------------
// Round-3 skeleton + two cheap overlaps (no extra live acc across barriers):
//   P1: x[t+1] loads issued; head(t-1) folded in; accA = b0 + Wih0*x[t] + Whh0*h0
//   a0 / g0 / b0
//   P2: x[t+1] LDS writes; accA = b1 + Wih1*h0_new + Whh1*h1_old
//   a1 / g1 / b1
//   P3: accA = b2 + Wih2*h1_new + Whh2*h2_old
//   a2 / g2 / b2
__global__ __launch_bounds__(THREADS, 2) void lstm_mfma(
    const float* __restrict__ x,
    const float* __restrict__ bih0, const float* __restrict__ bhh0,
    const float* __restrict__ bih1, const float* __restrict__ bhh1,
    const float* __restrict__ bih2, const float* __restrict__ bhh2,
    const float* __restrict__ bl,
    const _Float16* __restrict__ wsp,
    float* __restrict__ out)
{
    __shared__ _Float16 Hs[2][3][NROW][KP];    // [hi/lo][layer][m][k]  = 52224 B
    __shared__ _Float16 Xs[2][2][NROW][KP0];   // [buf][hi/lo][m][k]    = 10240 B
    __shared__ float    Bs[3][512];            // bih+bhh per layer     = 6144 B

    const int tid  = threadIdx.x;
    const int wv   = tid >> 6;
    const int lane = tid & 63;
    const int col  = lane & 15;
    const int quad = lane >> 4;
    const int q8   = quad * 8;
    const int b0   = blockIdx.x * NROW;

    // stage bias sums into LDS (saves persistent registers)
    for (int i = tid; i < 1536; i += THREADS) {
        int l = i >> 9, n = i & 511;
        const float* bi = (l == 0) ? bih0 : (l == 1) ? bih1 : bih2;
        const float* bh = (l == 0) ? bhh0 : (l == 1) ? bhh1 : bhh2;
        Bs[l][n] = bi[n] + bh[n];
    }
    // zero h state (hi+lo planes): 52224 B = 13056 floats
    for (int i = tid; i < 13056; i += THREADS) ((float*)Hs)[i] = 0.0f;

    // stage x[:, 0, :] as f16 hi/lo into buffer 0 (K padded to 32)
    for (int ii = tid; ii < NROW * 32; ii += THREADS) {
        int m = ii >> 5, k = ii & 31;
        float v = (k < INW) ? x[(size_t)(b0 + m) * (TSTEPS * INW) + k] : 0.0f;
        _Float16 hi = (_Float16)v;
        Xs[0][0][m][k] = hi;
        Xs[0][1][m][k] = (_Float16)(v - (float)hi);
    }

    f32x4 cst[3][2];
#pragma unroll
    for (int l = 0; l < 3; ++l) { cst[l][0] = (f32x4){0,0,0,0}; cst[l][1] = (f32x4){0,0,0,0}; }

    // weight pointers (fragment-ordered)
    const _Float16* Whh[3] = {wsp + W_BIG,  wsp + W_BIG + 131072, wsp + W_BIG + 262144};
    const _Float16* Wih[3] = {wsp + W_IH0, wsp + W_BIG + 393216, wsp + W_BIG + 524288};

    // head bias (waves 0..3 only)
    float blv = 0.0f;
    {
        int i = (wv & 1) * 16 + col;
        if (wv < 4 && i < INW) blv = bl[i];
    }

    __syncthreads();

    int tb = 0;
#pragma unroll 1
    for (int t = 0; t < TSTEPS; ++t) {
        f32x4 accA[2][4];
        const int nb = tb ^ 1;
        const int t2 = t + 1;

        // ---- phase 1: issue x[t+1] loads early; head(t-1); L0 full ----
        float xva[2];
        if (t2 < TSTEPS) {
#pragma unroll
            for (int u = 0; u < 2; ++u) {
                int ii = tid + u * THREADS;
                int m = ii >> 5, k = ii & 31;
                xva[u] = (k < INW) ? x[(size_t)(b0 + m) * (TSTEPS * INW) + t2 * INW + k] : 0.0f;
            }
        }
        if (t > 0 && wv < 4)
            head_out(wsp, &Hs[0][2][0][0], &Hs[1][2][0][0], out, b0, t - 1,
                     wv, lane, col, quad, q8, blv);
#pragma unroll
        for (int mt = 0; mt < 2; ++mt)
#pragma unroll
            for (int g = 0; g < 4; ++g) {
                float bv = Bs[0][g * 128 + wv * 16 + col];
                accA[mt][g] = (f32x4){bv, bv, bv, bv};
            }
        gemm_x(accA, &Xs[tb][0][0][0], &Xs[tb][1][0][0], Wih[0], col, q8, wv, lane);
        gemm_h(accA, &Hs[0][0][0][0], &Hs[1][0][0][0], Whh[0], col, q8, wv, lane);

        __syncthreads();   // a0: reads of Hs[0] / Xs[tb] complete
        gates_store(accA, cst[0], &Hs[0][0][0][0], &Hs[1][0][0][0], quad, col, wv);
        __syncthreads();   // b0: h0_new visible

        // ---- phase 2: write x[t+1] to LDS dbuf; L1 full ----
        if (t2 < TSTEPS) {
#pragma unroll
            for (int u = 0; u < 2; ++u) {
                int ii = tid + u * THREADS;
                int m = ii >> 5, k = ii & 31;
                _Float16 hi = (_Float16)xva[u];
                Xs[nb][0][m][k] = hi;
                Xs[nb][1][m][k] = (_Float16)(xva[u] - (float)hi);
            }
        }
#pragma unroll
        for (int mt = 0; mt < 2; ++mt)
#pragma unroll
            for (int g = 0; g < 4; ++g) {
                float bv = Bs[1][g * 128 + wv * 16 + col];
                accA[mt][g] = (f32x4){bv, bv, bv, bv};
            }
        gemm_h(accA, &Hs[0][0][0][0], &Hs[1][0][0][0], Wih[1], col, q8, wv, lane);
        gemm_h(accA, &Hs[0][1][0][0], &Hs[1][1][0][0], Whh[1], col, q8, wv, lane);

        __syncthreads();   // a1: reads of Hs[1] (and Hs[0]) complete
        gates_store(accA, cst[1], &Hs[0][1][0][0], &Hs[1][1][0][0], quad, col, wv);
        __syncthreads();   // b1: h1_new visible

        // ---- phase 3: L2 full ----
#pragma unroll
        for (int mt = 0; mt < 2; ++mt)
#pragma unroll
            for (int g = 0; g < 4; ++g) {
                float bv = Bs[2][g * 128 + wv * 16 + col];
                accA[mt][g] = (f32x4){bv, bv, bv, bv};
            }
        gemm_h(accA, &Hs[0][1][0][0], &Hs[1][1][0][0], Wih[2], col, q8, wv, lane);
        gemm_h(accA, &Hs[0][2][0][0], &Hs[1][2][0][0], Whh[2], col, q8, wv, lane);

        __syncthreads();   // a2: reads of Hs[2] (and Hs[1]) complete
        gates_store(accA, cst[2], &Hs[0][2][0][0], &Hs[1][2][0][0], quad, col, wv);
        __syncthreads();   // b2: h2_new visible (head reads it next iteration / epilogue)

        tb = nb;
    }

    // epilogue head for t = TSTEPS-1
    if (wv < 4)
        head_out(wsp, &Hs[0][2][0][0], &Hs[1][2][0][0], out, b0, TSTEPS - 1,
                 wv, lane, col, quad, q8, blv);
}

extern "C" void kernel_launch(void* const* d_in, const int* in_sizes, int n_in,
                              void* d_out, int out_size, void* d_ws, size_t ws_size,
                              hipStream_t stream) {
    const float* x    = (const float*)d_in[0];
    const float* Wih0 = (const float*)d_in[1];
    const float* Whh0 = (const float*)d_in[2];
    const float* bih0 = (const float*)d_in[3];
    const float* bhh0 = (const float*)d_in[4];
    const float* Wih1 = (const float*)d_in[5];
    const float* Whh1 = (const float*)d_in[6];
    const float* bih1 = (const float*)d_in[7];
    const float* bhh1 = (const float*)d_in[8];
    const float* Wih2 = (const float*)d_in[9];
    const float* Whh2 = (const float*)d_in[10];
    const float* bih2 = (const float*)d_in[11];
    const float* bhh2 = (const float*)d_in[12];
    const float* Wl   = (const float*)d_in[13];
    const float* bl   = (const float*)d_in[14];
    float* out = (float*)d_out;
    _Float16* ws = (_Float16*)d_ws;

    convert_w<<<(348160 + 255) / 256, 256, 0, stream>>>(Whh0, Whh1, Whh2, Wih1, Wih2, Wih0, Wl, ws);
    lstm_mfma<<<BATCH / NROW, THREADS, 0, stream>>>(
        x, bih0, bhh0, bih1, bhh1, bih2, bhh2, bl, ws, out);
}

// Round 7
// 741.021 us; speedup vs baseline: 4.1430x; 3.7606x over previous
//
#include <hip/hip_runtime.h>
#include <math.h>

#define BATCH  16384
#define TSTEPS 19
#define INW    17
#define HID    128
#define NROW   32          // batch rows per WG -> grid = 512 = 2 blocks/CU
#define THREADS 512        // 8 waves; wave wv owns j-tile wv (all 4 gates, both m-tiles)
#define KP     136         // padded row length (halfs) for h state (128+8)
#define KP0    40          // padded row length (halfs) for x (32+8)

typedef _Float16 f16x8 __attribute__((ext_vector_type(8)));
typedef float    f32x4 __attribute__((ext_vector_type(4)));

// ---- ws layout (halfs), MFMA-fragment-ordered tiles ----
#define W_BIG      0                 // 5 * 131072 = 655360
#define W_IH0      655360            // [512][32]: n_tile 0..31, tiles of 1024 (hi512|lo512)
#define W_HEAD     688128            // [32 rows][128]: (n_tile 0..1, ks 0..3) tiles of 1024
#define WS_HALFS   696320

__device__ __forceinline__ float fast_rcp(float x) { return __builtin_amdgcn_rcpf(x); }
__device__ __forceinline__ float sigm(float z)  { return fast_rcp(1.0f + __expf(-z)); }
__device__ __forceinline__ float tanh_(float z) { return 1.0f - 2.0f * fast_rcp(1.0f + __expf(2.0f * z)); }

// ---------------- weight conversion: fp32 -> f16 hi/lo, fragment order ----------------
__global__ void convert_w(const float* __restrict__ Whh0, const float* __restrict__ Whh1,
                          const float* __restrict__ Whh2, const float* __restrict__ Wih1,
                          const float* __restrict__ Wih2, const float* __restrict__ Wih0,
                          const float* __restrict__ Wl, _Float16* __restrict__ ws)
{
    int idx = blockIdx.x * 256 + threadIdx.x;
    if (idx < 327680) {
        int m = idx >> 16, e = idx & 65535;
        int r = e >> 7, k = e & 127;
        const float* src = (m == 0) ? Whh0 : (m == 1) ? Whh1 : (m == 2) ? Whh2
                          : (m == 3) ? Wih1 : Wih2;
        float v = src[e];
        _Float16 hi = (_Float16)v;
        int n_tile = r >> 4, colr = r & 15, ks = k >> 5, qd = (k >> 3) & 3, j = k & 7;
        int dst = W_BIG + m * 131072 + (n_tile * 4 + ks) * 1024 + (qd * 16 + colr) * 8 + j;
        ws[dst]       = hi;
        ws[dst + 512] = (_Float16)(v - (float)hi);
    } else if (idx < 344064) {
        int e = idx - 327680;              // [0, 16384)
        int r = e >> 5, k = e & 31;
        float v = (k < INW) ? Wih0[r * INW + k] : 0.0f;
        _Float16 hi = (_Float16)v;
        int n_tile = r >> 4, colr = r & 15, qd = k >> 3, j = k & 7;
        int dst = W_IH0 + n_tile * 1024 + (qd * 16 + colr) * 8 + j;
        ws[dst]       = hi;
        ws[dst + 512] = (_Float16)(v - (float)hi);
    } else if (idx < 348160) {
        int e = idx - 344064;              // [0, 4096)
        int r = e >> 7, k = e & 127;
        float v = (r < INW) ? Wl[(size_t)r * HID + k] : 0.0f;
        _Float16 hi = (_Float16)v;
        int n_tile = r >> 4, colr = r & 15, ks = k >> 5, qd = (k >> 3) & 3, j = k & 7;
        int dst = W_HEAD + (n_tile * 4 + ks) * 1024 + (qd * 16 + colr) * 8 + j;
        ws[dst]       = hi;
        ws[dst + 512] = (_Float16)(v - (float)hi);
    }
}

// ---------------- GEMM helpers (software-pipelined, sched_barrier-fenced) ----------------
// acc[mt][g]: rows m = mt*16 + quad*4 + r, cols n = g*128 + wv*16 + col
// A from LDS h planes (hi/lo, row-major stride KP); B fragment tiles (coalesced lane*8).
// Pipeline: B tiles double-buffered, issued 2 regions ahead; A frags double-buffered per ks.
__device__ __forceinline__ void gemm_h(f32x4 acc[2][4],
                                       const _Float16* __restrict__ Ahi,
                                       const _Float16* __restrict__ Alo,
                                       const _Float16* __restrict__ B,
                                       int col, int q8, int wv, int lane)
{
    const _Float16* a_h = Ahi + col * KP;
    const _Float16* a_l = Alo + col * KP;
    const int l8 = lane * 8;
    const _Float16* Bw = B + (wv * 4) * 1024 + l8;   // tile (ks,g) at Bw + (g*32+ks)*1024

    f16x8 bh[2], bl[2];
    f16x8 ah0[2], al0[2], ah1[2], al1[2];

    // prologue: A frags for ks=0; B tiles for regions 0,1
    ah0[0] = *(const f16x8*)(a_h + q8);
    al0[0] = *(const f16x8*)(a_l + q8);
    ah1[0] = *(const f16x8*)(a_h + 16 * KP + q8);
    al1[0] = *(const f16x8*)(a_l + 16 * KP + q8);
    bh[0] = *(const f16x8*)(Bw);
    bl[0] = *(const f16x8*)(Bw + 512);
    bh[1] = *(const f16x8*)(Bw + 32 * 1024);
    bl[1] = *(const f16x8*)(Bw + 32 * 1024 + 512);
    __builtin_amdgcn_sched_barrier(0);

#pragma unroll
    for (int it = 0; it < 16; ++it) {
        const int ks = it >> 2, g = it & 3;
        const int sl = it & 1;      // B slot
        const int ka = ks & 1;      // A slot
        __builtin_amdgcn_s_setprio(1);
        acc[0][g] = __builtin_amdgcn_mfma_f32_16x16x32_f16(ah0[ka], bh[sl], acc[0][g], 0, 0, 0);
        acc[0][g] = __builtin_amdgcn_mfma_f32_16x16x32_f16(al0[ka], bh[sl], acc[0][g], 0, 0, 0);
        acc[0][g] = __builtin_amdgcn_mfma_f32_16x16x32_f16(ah0[ka], bl[sl], acc[0][g], 0, 0, 0);
        acc[1][g] = __builtin_amdgcn_mfma_f32_16x16x32_f16(ah1[ka], bh[sl], acc[1][g], 0, 0, 0);
        acc[1][g] = __builtin_amdgcn_mfma_f32_16x16x32_f16(al1[ka], bh[sl], acc[1][g], 0, 0, 0);
        acc[1][g] = __builtin_amdgcn_mfma_f32_16x16x32_f16(ah1[ka], bl[sl], acc[1][g], 0, 0, 0);
        __builtin_amdgcn_s_setprio(0);
        // issue B loads for region it+2 (consumed 2 regions later)
        if (it < 14) {
            const int it2 = it + 2;
            const _Float16* p = Bw + (((it2) & 3) * 32 + ((it2) >> 2)) * 1024;
            bh[sl] = *(const f16x8*)(p);
            bl[sl] = *(const f16x8*)(p + 512);
        }
        // issue A frag loads for ks+1 early in each ks (consumed 4 regions later)
        if (g == 0 && ks < 3) {
            const int ko = (ks + 1) * 32 + q8;
            ah0[ka ^ 1] = *(const f16x8*)(a_h + ko);
            al0[ka ^ 1] = *(const f16x8*)(a_l + ko);
            ah1[ka ^ 1] = *(const f16x8*)(a_h + 16 * KP + ko);
            al1[ka ^ 1] = *(const f16x8*)(a_l + 16 * KP + ko);
        }
        __builtin_amdgcn_sched_barrier(0);   // pin the pipeline: nothing crosses
    }
}

// x-part for layer 0: K=32 (padded), 4 regions, same depth-2 B pipeline
__device__ __forceinline__ void gemm_x(f32x4 acc[2][4],
                                       const _Float16* __restrict__ Xhi,
                                       const _Float16* __restrict__ Xlo,
                                       const _Float16* __restrict__ B,
                                       int col, int q8, int wv, int lane)
{
    const int l8 = lane * 8;
    const _Float16* Bw = B + wv * 1024 + l8;         // tile g at Bw + g*8*1024
    f16x8 ah0 = *(const f16x8*)(Xhi + col * KP0 + q8);
    f16x8 al0 = *(const f16x8*)(Xlo + col * KP0 + q8);
    f16x8 ah1 = *(const f16x8*)(Xhi + (16 + col) * KP0 + q8);
    f16x8 al1 = *(const f16x8*)(Xlo + (16 + col) * KP0 + q8);
    f16x8 bh[2], bl[2];
    bh[0] = *(const f16x8*)(Bw);
    bl[0] = *(const f16x8*)(Bw + 512);
    bh[1] = *(const f16x8*)(Bw + 8 * 1024);
    bl[1] = *(const f16x8*)(Bw + 8 * 1024 + 512);
    __builtin_amdgcn_sched_barrier(0);
#pragma unroll
    for (int g = 0; g < 4; ++g) {
        const int sl = g & 1;
        __builtin_amdgcn_s_setprio(1);
        acc[0][g] = __builtin_amdgcn_mfma_f32_16x16x32_f16(ah0, bh[sl], acc[0][g], 0, 0, 0);
        acc[0][g] = __builtin_amdgcn_mfma_f32_16x16x32_f16(al0, bh[sl], acc[0][g], 0, 0, 0);
        acc[0][g] = __builtin_amdgcn_mfma_f32_16x16x32_f16(ah0, bl[sl], acc[0][g], 0, 0, 0);
        acc[1][g] = __builtin_amdgcn_mfma_f32_16x16x32_f16(ah1, bh[sl], acc[1][g], 0, 0, 0);
        acc[1][g] = __builtin_amdgcn_mfma_f32_16x16x32_f16(al1, bh[sl], acc[1][g], 0, 0, 0);
        acc[1][g] = __builtin_amdgcn_mfma_f32_16x16x32_f16(ah1, bl[sl], acc[1][g], 0, 0, 0);
        __builtin_amdgcn_s_setprio(0);
        if (g < 2) {
            const _Float16* p = Bw + (g + 2) * 8 * 1024;
            bh[sl] = *(const f16x8*)(p);
            bl[sl] = *(const f16x8*)(p + 512);
        }
        __builtin_amdgcn_sched_barrier(0);
    }
}

// gates + h write for one layer (acc consumed, cst updated, h hi/lo -> LDS)
__device__ __forceinline__ void gates_store(f32x4 acc[2][4], f32x4 cst[2],
                                            _Float16* __restrict__ HsHi,
                                            _Float16* __restrict__ HsLo,
                                            int quad, int col, int wv)
{
#pragma unroll
    for (int mt = 0; mt < 2; ++mt) {
#pragma unroll
        for (int r = 0; r < 4; ++r) {
            float zi = acc[mt][0][r];
            float zf = acc[mt][1][r];
            float zg = acc[mt][2][r];
            float zo = acc[mt][3][r];
            float ig = sigm(zi), fg = sigm(zf), og = sigm(zo), gg = tanh_(zg);
            float cn = fg * cst[mt][r] + ig * gg;
            cst[mt][r] = cn;
            float h = og * tanh_(cn);
            int m = mt * 16 + quad * 4 + r;
            int j = wv * 16 + col;
            _Float16 hh = (_Float16)h;
            HsHi[m * KP + j] = hh;
            HsLo[m * KP + j] = (_Float16)(h - (float)hh);
        }
    }
}

// out[:, t, :] = h2 @ Wl^T + bl (waves 0..3 only: mt = wv>>1, nt = wv&1)
__device__ __forceinline__ void head_out(const _Float16* __restrict__ wsp,
                                         const _Float16* __restrict__ HsHi2,
                                         const _Float16* __restrict__ HsLo2,
                                         float* __restrict__ out, int b0, int t,
                                         int wv, int lane, int col, int quad, int q8,
                                         float blv)
{
    const int mt = wv >> 1, nt = wv & 1;
    const _Float16* ah = HsHi2 + (mt * 16 + col) * KP;
    const _Float16* al = HsLo2 + (mt * 16 + col) * KP;
    f32x4 o = (f32x4){0, 0, 0, 0};
#pragma unroll
    for (int ks = 0; ks < 4; ++ks) {
        const _Float16* bt = wsp + W_HEAD + (nt * 4 + ks) * 1024 + lane * 8;
        f16x8 a_h = *(const f16x8*)(ah + ks * 32 + q8);
        f16x8 a_l = *(const f16x8*)(al + ks * 32 + q8);
        f16x8 b_h = *(const f16x8*)(bt);
        f16x8 b_l = *(const f16x8*)(bt + 512);
        o = __builtin_amdgcn_mfma_f32_16x16x32_f16(a_h, b_h, o, 0, 0, 0);
        o = __builtin_amdgcn_mfma_f32_16x16x32_f16(a_l, b_h, o, 0, 0, 0);
        o = __builtin_amdgcn_mfma_f32_16x16x32_f16(a_h, b_l, o, 0, 0, 0);
    }
    int i = nt * 16 + col;
    if (i < INW) {
#pragma unroll
        for (int r = 0; r < 4; ++r) {
            int m = mt * 16 + quad * 4 + r;
            out[(size_t)(b0 + m) * (TSTEPS * INW) + t * INW + i] = o[r] + blv;
        }
    }
}

// ---------------- main kernel ----------------
// Round-3 rolled layer loop (compact body -> compact regalloc), with the cheap
// overlaps as conditionals INSIDE the loop:
//   l==0: issue x[t+1] loads; head(t-1) on waves 0..3; L0 gemms
//   l==1: write x[t+1] to Xs dbuf; L1 gemms
//   l==2: L2 gemms
// 6 barriers/timestep (head window eliminated).
__global__ __launch_bounds__(THREADS, 2) void lstm_mfma(
    const float* __restrict__ x,
    const float* __restrict__ bih0, const float* __restrict__ bhh0,
    const float* __restrict__ bih1, const float* __restrict__ bhh1,
    const float* __restrict__ bih2, const float* __restrict__ bhh2,
    const float* __restrict__ bl,
    const _Float16* __restrict__ wsp,
    float* __restrict__ out)
{
    __shared__ _Float16 Hs[2][3][NROW][KP];    // [hi/lo][layer][m][k]  = 52224 B
    __shared__ _Float16 Xs[2][2][NROW][KP0];   // [buf][hi/lo][m][k]    = 10240 B
    __shared__ float    Bs[3][512];            // bih+bhh per layer     = 6144 B

    const int tid  = threadIdx.x;
    const int wv   = tid >> 6;
    const int lane = tid & 63;
    const int col  = lane & 15;
    const int quad = lane >> 4;
    const int q8   = quad * 8;
    const int b0   = blockIdx.x * NROW;

    // stage bias sums into LDS (saves persistent registers)
    for (int i = tid; i < 1536; i += THREADS) {
        int l = i >> 9, n = i & 511;
        const float* bi = (l == 0) ? bih0 : (l == 1) ? bih1 : bih2;
        const float* bh = (l == 0) ? bhh0 : (l == 1) ? bhh1 : bhh2;
        Bs[l][n] = bi[n] + bh[n];
    }
    // zero h state (hi+lo planes): 52224 B = 13056 floats
    for (int i = tid; i < 13056; i += THREADS) ((float*)Hs)[i] = 0.0f;

    // stage x[:, 0, :] as f16 hi/lo into buffer 0 (K padded to 32)
    for (int ii = tid; ii < NROW * 32; ii += THREADS) {
        int m = ii >> 5, k = ii & 31;
        float v = (k < INW) ? x[(size_t)(b0 + m) * (TSTEPS * INW) + k] : 0.0f;
        _Float16 hi = (_Float16)v;
        Xs[0][0][m][k] = hi;
        Xs[0][1][m][k] = (_Float16)(v - (float)hi);
    }

    f32x4 cst[3][2];
#pragma unroll
    for (int l = 0; l < 3; ++l) { cst[l][0] = (f32x4){0,0,0,0}; cst[l][1] = (f32x4){0,0,0,0}; }

    // weight pointers (fragment-ordered)
    const _Float16* Whh[3] = {wsp + W_BIG,  wsp + W_BIG + 131072, wsp + W_BIG + 262144};
    const _Float16* Wih[3] = {wsp + W_IH0, wsp + W_BIG + 393216, wsp + W_BIG + 524288};

    // head bias (waves 0..3 only)
    float blv = 0.0f;
    {
        int i = (wv & 1) * 16 + col;
        if (wv < 4 && i < INW) blv = bl[i];
    }

    __syncthreads();

    int tb = 0;
#pragma unroll 1
    for (int t = 0; t < TSTEPS; ++t) {
        const int nb = tb ^ 1;
        const int t2 = t + 1;
        float xva[2];

#pragma unroll 1
        for (int l = 0; l < 3; ++l) {
            if (l == 0) {
                // issue x[t+1] loads early (latency hides under head + L0 gemms)
                if (t2 < TSTEPS) {
#pragma unroll
                    for (int u = 0; u < 2; ++u) {
                        int ii = tid + u * THREADS;
                        int m = ii >> 5, k = ii & 31;
                        xva[u] = (k < INW) ? x[(size_t)(b0 + m) * (TSTEPS * INW) + t2 * INW + k] : 0.0f;
                    }
                }
                // head for t-1 folded into this gemm stretch (waves 0..3)
                if (t > 0 && wv < 4)
                    head_out(wsp, &Hs[0][2][0][0], &Hs[1][2][0][0], out, b0, t - 1,
                             wv, lane, col, quad, q8, blv);
            } else if (l == 1) {
                // write x[t+1] to the LDS double-buffer (loads long since landed)
                if (t2 < TSTEPS) {
#pragma unroll
                    for (int u = 0; u < 2; ++u) {
                        int ii = tid + u * THREADS;
                        int m = ii >> 5, k = ii & 31;
                        _Float16 hi = (_Float16)xva[u];
                        Xs[nb][0][m][k] = hi;
                        Xs[nb][1][m][k] = (_Float16)(xva[u] - (float)hi);
                    }
                }
            }

            f32x4 acc[2][4];
#pragma unroll
            for (int mt = 0; mt < 2; ++mt)
#pragma unroll
                for (int g = 0; g < 4; ++g) {
                    float bv = Bs[l][g * 128 + wv * 16 + col];
                    acc[mt][g] = (f32x4){bv, bv, bv, bv};
                }

            // input contribution
            if (l == 0)
                gemm_x(acc, &Xs[tb][0][0][0], &Xs[tb][1][0][0], Wih[0], col, q8, wv, lane);
            else
                gemm_h(acc, &Hs[0][l - 1][0][0], &Hs[1][l - 1][0][0], Wih[l], col, q8, wv, lane);
            // recurrent contribution
            gemm_h(acc, &Hs[0][l][0][0], &Hs[1][l][0][0], Whh[l], col, q8, wv, lane);

            __syncthreads();   // all reads of Hs[l] (and Hs[l-1] / Xs) complete
            gates_store(acc, cst[l], &Hs[0][l][0][0], &Hs[1][l][0][0], quad, col, wv);
            __syncthreads();   // new h visible
        }

        tb = nb;
    }

    // epilogue head for t = TSTEPS-1
    if (wv < 4)
        head_out(wsp, &Hs[0][2][0][0], &Hs[1][2][0][0], out, b0, TSTEPS - 1,
                 wv, lane, col, quad, q8, blv);
}

extern "C" void kernel_launch(void* const* d_in, const int* in_sizes, int n_in,
                              void* d_out, int out_size, void* d_ws, size_t ws_size,
                              hipStream_t stream) {
    const float* x    = (const float*)d_in[0];
    const float* Wih0 = (const float*)d_in[1];
    const float* Whh0 = (const float*)d_in[2];
    const float* bih0 = (const float*)d_in[3];
    const float* bhh0 = (const float*)d_in[4];
    const float* Wih1 = (const float*)d_in[5];
    const float* Whh1 = (const float*)d_in[6];
    const float* bih1 = (const float*)d_in[7];
    const float* bhh1 = (const float*)d_in[8];
    const float* Wih2 = (const float*)d_in[9];
    const float* Whh2 = (const float*)d_in[10];
    const float* bih2 = (const float*)d_in[11];
    const float* bhh2 = (const float*)d_in[12];
    const float* Wl   = (const float*)d_in[13];
    const float* bl   = (const float*)d_in[14];
    float* out = (float*)d_out;
    _Float16* ws = (_Float16*)d_ws;

    convert_w<<<(348160 + 255) / 256, 256, 0, stream>>>(Whh0, Whh1, Whh2, Wih1, Wih2, Wih0, Wl, ws);
    lstm_mfma<<<BATCH / NROW, THREADS, 0, stream>>>(
        x, bih0, bhh0, bih1, bhh1, bih2, bhh2, bl, ws, out);
}

// Round 8
// 735.789 us; speedup vs baseline: 4.1725x; 1.0071x over previous
//
#include <hip/hip_runtime.h>
#include <math.h>

#define BATCH  16384
#define TSTEPS 19
#define INW    17
#define HID    128
#define NROW   32          // batch rows per WG -> grid = 512 = 2 blocks/CU
#define THREADS 512        // 8 waves; wave wv owns j-tile wv (all 4 gates, both m-tiles)
#define KP     136         // padded row length (halfs) for h state (128+8)
#define KP0    40          // padded row length (halfs) for x (32+8)

typedef _Float16 f16x8 __attribute__((ext_vector_type(8)));
typedef float    f32x4 __attribute__((ext_vector_type(4)));

// ---- ws layout (halfs), MFMA-fragment-ordered tiles ----
#define W_BIG      0                 // 5 * 131072 = 655360
#define W_IH0      655360            // [512][32]: n_tile 0..31, tiles of 1024 (hi512|lo512)
#define W_HEAD     688128            // [32 rows][128]: (n_tile 0..1, ks 0..3) tiles of 1024
#define WS_HALFS   696320

__device__ __forceinline__ float fast_rcp(float x) { return __builtin_amdgcn_rcpf(x); }
__device__ __forceinline__ float sigm(float z)  { return fast_rcp(1.0f + __expf(-z)); }
__device__ __forceinline__ float tanh_(float z) { return 1.0f - 2.0f * fast_rcp(1.0f + __expf(2.0f * z)); }

// ---------------- weight conversion: fp32 -> f16 hi/lo, fragment order ----------------
__global__ void convert_w(const float* __restrict__ Whh0, const float* __restrict__ Whh1,
                          const float* __restrict__ Whh2, const float* __restrict__ Wih1,
                          const float* __restrict__ Wih2, const float* __restrict__ Wih0,
                          const float* __restrict__ Wl, _Float16* __restrict__ ws)
{
    int idx = blockIdx.x * 256 + threadIdx.x;
    if (idx < 327680) {
        int m = idx >> 16, e = idx & 65535;
        int r = e >> 7, k = e & 127;
        const float* src = (m == 0) ? Whh0 : (m == 1) ? Whh1 : (m == 2) ? Whh2
                          : (m == 3) ? Wih1 : Wih2;
        float v = src[e];
        _Float16 hi = (_Float16)v;
        int n_tile = r >> 4, colr = r & 15, ks = k >> 5, qd = (k >> 3) & 3, j = k & 7;
        int dst = W_BIG + m * 131072 + (n_tile * 4 + ks) * 1024 + (qd * 16 + colr) * 8 + j;
        ws[dst]       = hi;
        ws[dst + 512] = (_Float16)(v - (float)hi);
    } else if (idx < 344064) {
        int e = idx - 327680;              // [0, 16384)
        int r = e >> 5, k = e & 31;
        float v = (k < INW) ? Wih0[r * INW + k] : 0.0f;
        _Float16 hi = (_Float16)v;
        int n_tile = r >> 4, colr = r & 15, qd = k >> 3, j = k & 7;
        int dst = W_IH0 + n_tile * 1024 + (qd * 16 + colr) * 8 + j;
        ws[dst]       = hi;
        ws[dst + 512] = (_Float16)(v - (float)hi);
    } else if (idx < 348160) {
        int e = idx - 344064;              // [0, 4096)
        int r = e >> 7, k = e & 127;
        float v = (r < INW) ? Wl[(size_t)r * HID + k] : 0.0f;
        _Float16 hi = (_Float16)v;
        int n_tile = r >> 4, colr = r & 15, ks = k >> 5, qd = (k >> 3) & 3, j = k & 7;
        int dst = W_HEAD + (n_tile * 4 + ks) * 1024 + (qd * 16 + colr) * 8 + j;
        ws[dst]       = hi;
        ws[dst + 512] = (_Float16)(v - (float)hi);
    }
}

// ---------------- GEMM helpers (software-pipelined, sched_barrier-fenced) ----------------
// acc[mt][g]: rows m = mt*16 + quad*4 + r, cols n = g*128 + wv*16 + col
// A from LDS h planes (hi/lo, row-major stride KP); B fragment tiles (coalesced lane*8).
// Pipeline: B tiles double-buffered, issued 2 regions ahead; A frags double-buffered per ks.
__device__ __forceinline__ void gemm_h(f32x4 acc[2][4],
                                       const _Float16* __restrict__ Ahi,
                                       const _Float16* __restrict__ Alo,
                                       const _Float16* __restrict__ B,
                                       int col, int q8, int wv, int lane)
{
    const _Float16* a_h = Ahi + col * KP;
    const _Float16* a_l = Alo + col * KP;
    const int l8 = lane * 8;
    const _Float16* Bw = B + (wv * 4) * 1024 + l8;   // tile (ks,g) at Bw + (g*32+ks)*1024

    f16x8 bh[2], bl[2];
    f16x8 ah0[2], al0[2], ah1[2], al1[2];

    // prologue: A frags for ks=0; B tiles for regions 0,1
    ah0[0] = *(const f16x8*)(a_h + q8);
    al0[0] = *(const f16x8*)(a_l + q8);
    ah1[0] = *(const f16x8*)(a_h + 16 * KP + q8);
    al1[0] = *(const f16x8*)(a_l + 16 * KP + q8);
    bh[0] = *(const f16x8*)(Bw);
    bl[0] = *(const f16x8*)(Bw + 512);
    bh[1] = *(const f16x8*)(Bw + 32 * 1024);
    bl[1] = *(const f16x8*)(Bw + 32 * 1024 + 512);
    __builtin_amdgcn_sched_barrier(0);

#pragma unroll
    for (int it = 0; it < 16; ++it) {
        const int ks = it >> 2, g = it & 3;
        const int sl = it & 1;      // B slot
        const int ka = ks & 1;      // A slot
        __builtin_amdgcn_s_setprio(1);
        acc[0][g] = __builtin_amdgcn_mfma_f32_16x16x32_f16(ah0[ka], bh[sl], acc[0][g], 0, 0, 0);
        acc[0][g] = __builtin_amdgcn_mfma_f32_16x16x32_f16(al0[ka], bh[sl], acc[0][g], 0, 0, 0);
        acc[0][g] = __builtin_amdgcn_mfma_f32_16x16x32_f16(ah0[ka], bl[sl], acc[0][g], 0, 0, 0);
        acc[1][g] = __builtin_amdgcn_mfma_f32_16x16x32_f16(ah1[ka], bh[sl], acc[1][g], 0, 0, 0);
        acc[1][g] = __builtin_amdgcn_mfma_f32_16x16x32_f16(al1[ka], bh[sl], acc[1][g], 0, 0, 0);
        acc[1][g] = __builtin_amdgcn_mfma_f32_16x16x32_f16(ah1[ka], bl[sl], acc[1][g], 0, 0, 0);
        __builtin_amdgcn_s_setprio(0);
        // issue B loads for region it+2 (consumed 2 regions later)
        if (it < 14) {
            const int it2 = it + 2;
            const _Float16* p = Bw + (((it2) & 3) * 32 + ((it2) >> 2)) * 1024;
            bh[sl] = *(const f16x8*)(p);
            bl[sl] = *(const f16x8*)(p + 512);
        }
        // issue A frag loads for ks+1 early in each ks (consumed 4 regions later)
        if (g == 0 && ks < 3) {
            const int ko = (ks + 1) * 32 + q8;
            ah0[ka ^ 1] = *(const f16x8*)(a_h + ko);
            al0[ka ^ 1] = *(const f16x8*)(a_l + ko);
            ah1[ka ^ 1] = *(const f16x8*)(a_h + 16 * KP + ko);
            al1[ka ^ 1] = *(const f16x8*)(a_l + 16 * KP + ko);
        }
        __builtin_amdgcn_sched_barrier(0);   // pin the pipeline: nothing crosses
    }
}

// x-part for layer 0: K=32 (padded), 4 regions, same depth-2 B pipeline
__device__ __forceinline__ void gemm_x(f32x4 acc[2][4],
                                       const _Float16* __restrict__ Xhi,
                                       const _Float16* __restrict__ Xlo,
                                       const _Float16* __restrict__ B,
                                       int col, int q8, int wv, int lane)
{
    const int l8 = lane * 8;
    const _Float16* Bw = B + wv * 1024 + l8;         // tile g at Bw + g*8*1024
    f16x8 ah0 = *(const f16x8*)(Xhi + col * KP0 + q8);
    f16x8 al0 = *(const f16x8*)(Xlo + col * KP0 + q8);
    f16x8 ah1 = *(const f16x8*)(Xhi + (16 + col) * KP0 + q8);
    f16x8 al1 = *(const f16x8*)(Xlo + (16 + col) * KP0 + q8);
    f16x8 bh[2], bl[2];
    bh[0] = *(const f16x8*)(Bw);
    bl[0] = *(const f16x8*)(Bw + 512);
    bh[1] = *(const f16x8*)(Bw + 8 * 1024);
    bl[1] = *(const f16x8*)(Bw + 8 * 1024 + 512);
    __builtin_amdgcn_sched_barrier(0);
#pragma unroll
    for (int g = 0; g < 4; ++g) {
        const int sl = g & 1;
        __builtin_amdgcn_s_setprio(1);
        acc[0][g] = __builtin_amdgcn_mfma_f32_16x16x32_f16(ah0, bh[sl], acc[0][g], 0, 0, 0);
        acc[0][g] = __builtin_amdgcn_mfma_f32_16x16x32_f16(al0, bh[sl], acc[0][g], 0, 0, 0);
        acc[0][g] = __builtin_amdgcn_mfma_f32_16x16x32_f16(ah0, bl[sl], acc[0][g], 0, 0, 0);
        acc[1][g] = __builtin_amdgcn_mfma_f32_16x16x32_f16(ah1, bh[sl], acc[1][g], 0, 0, 0);
        acc[1][g] = __builtin_amdgcn_mfma_f32_16x16x32_f16(al1, bh[sl], acc[1][g], 0, 0, 0);
        acc[1][g] = __builtin_amdgcn_mfma_f32_16x16x32_f16(ah1, bl[sl], acc[1][g], 0, 0, 0);
        __builtin_amdgcn_s_setprio(0);
        if (g < 2) {
            const _Float16* p = Bw + (g + 2) * 8 * 1024;
            bh[sl] = *(const f16x8*)(p);
            bl[sl] = *(const f16x8*)(p + 512);
        }
        __builtin_amdgcn_sched_barrier(0);
    }
}

// gates + h write for one layer (acc consumed, cst updated, h hi/lo -> LDS)
__device__ __forceinline__ void gates_store(f32x4 acc[2][4], f32x4 cst[2],
                                            _Float16* __restrict__ HsHi,
                                            _Float16* __restrict__ HsLo,
                                            int quad, int col, int wv)
{
#pragma unroll
    for (int mt = 0; mt < 2; ++mt) {
#pragma unroll
        for (int r = 0; r < 4; ++r) {
            float zi = acc[mt][0][r];
            float zf = acc[mt][1][r];
            float zg = acc[mt][2][r];
            float zo = acc[mt][3][r];
            float ig = sigm(zi), fg = sigm(zf), og = sigm(zo), gg = tanh_(zg);
            float cn = fg * cst[mt][r] + ig * gg;
            cst[mt][r] = cn;
            float h = og * tanh_(cn);
            int m = mt * 16 + quad * 4 + r;
            int j = wv * 16 + col;
            _Float16 hh = (_Float16)h;
            HsHi[m * KP + j] = hh;
            HsLo[m * KP + j] = (_Float16)(h - (float)hh);
        }
    }
}

// out[:, t, :] = h2 @ Wl^T + bl (waves 0..3 only: mt = wv>>1, nt = wv&1)
__device__ __forceinline__ void head_out(const _Float16* __restrict__ wsp,
                                         const _Float16* __restrict__ HsHi2,
                                         const _Float16* __restrict__ HsLo2,
                                         float* __restrict__ out, int b0, int t,
                                         int wv, int lane, int col, int quad, int q8,
                                         float blv)
{
    const int mt = wv >> 1, nt = wv & 1;
    const _Float16* ah = HsHi2 + (mt * 16 + col) * KP;
    const _Float16* al = HsLo2 + (mt * 16 + col) * KP;
    f32x4 o = (f32x4){0, 0, 0, 0};
#pragma unroll
    for (int ks = 0; ks < 4; ++ks) {
        const _Float16* bt = wsp + W_HEAD + (nt * 4 + ks) * 1024 + lane * 8;
        f16x8 a_h = *(const f16x8*)(ah + ks * 32 + q8);
        f16x8 a_l = *(const f16x8*)(al + ks * 32 + q8);
        f16x8 b_h = *(const f16x8*)(bt);
        f16x8 b_l = *(const f16x8*)(bt + 512);
        o = __builtin_amdgcn_mfma_f32_16x16x32_f16(a_h, b_h, o, 0, 0, 0);
        o = __builtin_amdgcn_mfma_f32_16x16x32_f16(a_l, b_h, o, 0, 0, 0);
        o = __builtin_amdgcn_mfma_f32_16x16x32_f16(a_h, b_l, o, 0, 0, 0);
    }
    int i = nt * 16 + col;
    if (i < INW) {
#pragma unroll
        for (int r = 0; r < 4; ++r) {
            int m = mt * 16 + quad * 4 + r;
            out[(size_t)(b0 + m) * (TSTEPS * INW) + t * INW + i] = o[r] + blv;
        }
    }
}

// ---------------- main kernel ----------------
// 3-barrier schedule. Per layer iteration:
//   rec-gemm Whh(l)*h_old(l)  [+ gemm_x / x-loads at l==0; Xs write at l==1; head(t-1) at l==2]
//   BARRIER   (anti-dep: all reads of Hs[l]-old done; visibility: h_new(l-1) published)
//   in-gemm Wih(l)*h_new(l-1)  [l>0]
//   gates(l) -> write Hs[l]
// After gates, the wave flows straight into the next layer's rec gemm (no barrier).
__global__ __launch_bounds__(THREADS, 2) void lstm_mfma(
    const float* __restrict__ x,
    const float* __restrict__ bih0, const float* __restrict__ bhh0,
    const float* __restrict__ bih1, const float* __restrict__ bhh1,
    const float* __restrict__ bih2, const float* __restrict__ bhh2,
    const float* __restrict__ bl,
    const _Float16* __restrict__ wsp,
    float* __restrict__ out)
{
    __shared__ _Float16 Hs[2][3][NROW][KP];    // [hi/lo][layer][m][k]  = 52224 B
    __shared__ _Float16 Xs[2][2][NROW][KP0];   // [buf][hi/lo][m][k]    = 10240 B
    __shared__ float    Bs[3][512];            // bih+bhh per layer     = 6144 B

    const int tid  = threadIdx.x;
    const int wv   = tid >> 6;
    const int lane = tid & 63;
    const int col  = lane & 15;
    const int quad = lane >> 4;
    const int q8   = quad * 8;
    const int b0   = blockIdx.x * NROW;

    // stage bias sums into LDS (saves persistent registers)
    for (int i = tid; i < 1536; i += THREADS) {
        int l = i >> 9, n = i & 511;
        const float* bi = (l == 0) ? bih0 : (l == 1) ? bih1 : bih2;
        const float* bh = (l == 0) ? bhh0 : (l == 1) ? bhh1 : bhh2;
        Bs[l][n] = bi[n] + bh[n];
    }
    // zero h state (hi+lo planes): 52224 B = 13056 floats
    for (int i = tid; i < 13056; i += THREADS) ((float*)Hs)[i] = 0.0f;

    // stage x[:, 0, :] as f16 hi/lo into buffer 0 (K padded to 32)
    for (int ii = tid; ii < NROW * 32; ii += THREADS) {
        int m = ii >> 5, k = ii & 31;
        float v = (k < INW) ? x[(size_t)(b0 + m) * (TSTEPS * INW) + k] : 0.0f;
        _Float16 hi = (_Float16)v;
        Xs[0][0][m][k] = hi;
        Xs[0][1][m][k] = (_Float16)(v - (float)hi);
    }

    f32x4 cst[3][2];
#pragma unroll
    for (int l = 0; l < 3; ++l) { cst[l][0] = (f32x4){0,0,0,0}; cst[l][1] = (f32x4){0,0,0,0}; }

    // weight pointers (fragment-ordered)
    const _Float16* Whh[3] = {wsp + W_BIG,  wsp + W_BIG + 131072, wsp + W_BIG + 262144};
    const _Float16* Wih[3] = {wsp + W_IH0, wsp + W_BIG + 393216, wsp + W_BIG + 524288};

    // head bias (waves 0..3 only)
    float blv = 0.0f;
    {
        int i = (wv & 1) * 16 + col;
        if (wv < 4 && i < INW) blv = bl[i];
    }

    __syncthreads();

    int tb = 0;
#pragma unroll 1
    for (int t = 0; t < TSTEPS; ++t) {
        const int nb = tb ^ 1;
        const int t2 = t + 1;
        float xva[2];

#pragma unroll 1
        for (int l = 0; l < 3; ++l) {
            f32x4 acc[2][4];
#pragma unroll
            for (int mt = 0; mt < 2; ++mt)
#pragma unroll
                for (int g = 0; g < 4; ++g) {
                    float bv = Bs[l][g * 128 + wv * 16 + col];
                    acc[mt][g] = (f32x4){bv, bv, bv, bv};
                }

            if (l == 0) {
                // issue x[t+1] loads early (latency hides under the L0 gemms)
                if (t2 < TSTEPS) {
#pragma unroll
                    for (int u = 0; u < 2; ++u) {
                        int ii = tid + u * THREADS;
                        int m = ii >> 5, k = ii & 31;
                        xva[u] = (k < INW) ? x[(size_t)(b0 + m) * (TSTEPS * INW) + t2 * INW + k] : 0.0f;
                    }
                }
                gemm_x(acc, &Xs[tb][0][0][0], &Xs[tb][1][0][0], Wih[0], col, q8, wv, lane);
            }

            // recurrent contribution (reads Hs[l] OLD)
            gemm_h(acc, &Hs[0][l][0][0], &Hs[1][l][0][0], Whh[l], col, q8, wv, lane);

            if (l == 1 && t2 < TSTEPS) {
                // write x[t+1] to the LDS double-buffer (loads landed during L0/L1 gemms)
#pragma unroll
                for (int u = 0; u < 2; ++u) {
                    int ii = tid + u * THREADS;
                    int m = ii >> 5, k = ii & 31;
                    _Float16 hi = (_Float16)xva[u];
                    Xs[nb][0][m][k] = hi;
                    Xs[nb][1][m][k] = (_Float16)(xva[u] - (float)hi);
                }
            }
            if (l == 2 && t > 0 && wv < 4)
                head_out(wsp, &Hs[0][2][0][0], &Hs[1][2][0][0], out, b0, t - 1,
                         wv, lane, col, quad, q8, blv);

            __syncthreads();   // reads of Hs[l]-old done (all waves); h_new(l-1) visible

            // input contribution (reads Hs[l-1] NEW)
            if (l > 0)
                gemm_h(acc, &Hs[0][l - 1][0][0], &Hs[1][l - 1][0][0], Wih[l], col, q8, wv, lane);

            gates_store(acc, cst[l], &Hs[0][l][0][0], &Hs[1][l][0][0], quad, col, wv);
            // no barrier here: next iteration's rec gemm touches a different Hs buffer
        }

        tb = nb;
    }

    __syncthreads();   // h2(T-1) visible for the epilogue head
    if (wv < 4)
        head_out(wsp, &Hs[0][2][0][0], &Hs[1][2][0][0], out, b0, TSTEPS - 1,
                 wv, lane, col, quad, q8, blv);
}

extern "C" void kernel_launch(void* const* d_in, const int* in_sizes, int n_in,
                              void* d_out, int out_size, void* d_ws, size_t ws_size,
                              hipStream_t stream) {
    const float* x    = (const float*)d_in[0];
    const float* Wih0 = (const float*)d_in[1];
    const float* Whh0 = (const float*)d_in[2];
    const float* bih0 = (const float*)d_in[3];
    const float* bhh0 = (const float*)d_in[4];
    const float* Wih1 = (const float*)d_in[5];
    const float* Whh1 = (const float*)d_in[6];
    const float* bih1 = (const float*)d_in[7];
    const float* bhh1 = (const float*)d_in[8];
    const float* Wih2 = (const float*)d_in[9];
    const float* Whh2 = (const float*)d_in[10];
    const float* bih2 = (const float*)d_in[11];
    const float* bhh2 = (const float*)d_in[12];
    const float* Wl   = (const float*)d_in[13];
    const float* bl   = (const float*)d_in[14];
    float* out = (float*)d_out;
    _Float16* ws = (_Float16*)d_ws;

    convert_w<<<(348160 + 255) / 256, 256, 0, stream>>>(Whh0, Whh1, Whh2, Wih1, Wih2, Wih0, Wl, ws);
    lstm_mfma<<<BATCH / NROW, THREADS, 0, stream>>>(
        x, bih0, bhh0, bih1, bhh1, bih2, bhh2, bl, ws, out);
}

// Round 9
// 725.027 us; speedup vs baseline: 4.2344x; 1.0148x over previous
//
#include <hip/hip_runtime.h>
#include <math.h>

#define BATCH  16384
#define TSTEPS 19
#define INW    17
#define HID    128
#define NROW   32          // batch rows per WG -> grid = 512 = 2 blocks/CU
#define THREADS 512        // 8 waves; wave wv owns j-tile wv (all 4 gates, both m-tiles)
#define KP     136         // padded row length (halfs) for h state (128+8)
#define KP0    40          // padded row length (halfs) for x (32+8)

typedef _Float16 f16x8 __attribute__((ext_vector_type(8)));
typedef float    f32x4 __attribute__((ext_vector_type(4)));

// ---- ws layout (halfs), MFMA-fragment-ordered tiles ----
#define W_BIG      0                 // 5 * 131072 = 655360
#define W_IH0      655360            // [512][32]: n_tile 0..31, tiles of 1024 (hi512|lo512)
#define W_HEAD     688128            // [32 rows][128]: (n_tile 0..1, ks 0..3) tiles of 1024
#define WS_HALFS   696320

__device__ __forceinline__ float fast_rcp(float x) { return __builtin_amdgcn_rcpf(x); }
__device__ __forceinline__ float sigm(float z)  { return fast_rcp(1.0f + __expf(-z)); }
__device__ __forceinline__ float tanh_(float z) { return 1.0f - 2.0f * fast_rcp(1.0f + __expf(2.0f * z)); }

// ---------------- weight conversion: fp32 -> f16 hi/lo, fragment order ----------------
__global__ void convert_w(const float* __restrict__ Whh0, const float* __restrict__ Whh1,
                          const float* __restrict__ Whh2, const float* __restrict__ Wih1,
                          const float* __restrict__ Wih2, const float* __restrict__ Wih0,
                          const float* __restrict__ Wl, _Float16* __restrict__ ws)
{
    int idx = blockIdx.x * 256 + threadIdx.x;
    if (idx < 327680) {
        int m = idx >> 16, e = idx & 65535;
        int r = e >> 7, k = e & 127;
        const float* src = (m == 0) ? Whh0 : (m == 1) ? Whh1 : (m == 2) ? Whh2
                          : (m == 3) ? Wih1 : Wih2;
        float v = src[e];
        _Float16 hi = (_Float16)v;
        int n_tile = r >> 4, colr = r & 15, ks = k >> 5, qd = (k >> 3) & 3, j = k & 7;
        int dst = W_BIG + m * 131072 + (n_tile * 4 + ks) * 1024 + (qd * 16 + colr) * 8 + j;
        ws[dst]       = hi;
        ws[dst + 512] = (_Float16)(v - (float)hi);
    } else if (idx < 344064) {
        int e = idx - 327680;              // [0, 16384)
        int r = e >> 5, k = e & 31;
        float v = (k < INW) ? Wih0[r * INW + k] : 0.0f;
        _Float16 hi = (_Float16)v;
        int n_tile = r >> 4, colr = r & 15, qd = k >> 3, j = k & 7;
        int dst = W_IH0 + n_tile * 1024 + (qd * 16 + colr) * 8 + j;
        ws[dst]       = hi;
        ws[dst + 512] = (_Float16)(v - (float)hi);
    } else if (idx < 348160) {
        int e = idx - 344064;              // [0, 4096)
        int r = e >> 7, k = e & 127;
        float v = (r < INW) ? Wl[(size_t)r * HID + k] : 0.0f;
        _Float16 hi = (_Float16)v;
        int n_tile = r >> 4, colr = r & 15, ks = k >> 5, qd = (k >> 3) & 3, j = k & 7;
        int dst = W_HEAD + (n_tile * 4 + ks) * 1024 + (qd * 16 + colr) * 8 + j;
        ws[dst]       = hi;
        ws[dst + 512] = (_Float16)(v - (float)hi);
    }
}

// ---------------- GEMM helpers (software-pipelined, sched_barrier-fenced) ----------------
// acc[mt][g]: rows m = mt*16 + quad*4 + r, cols n = g*128 + wv*16 + col
// A from LDS h planes (hi/lo, row-major stride KP); B fragment tiles (coalesced lane*8).
// Pipeline: B tiles 4-slot (issued 4 regions ahead ~= L2 latency); A frags dbuf per ks.
__device__ __forceinline__ void gemm_h(f32x4 acc[2][4],
                                       const _Float16* __restrict__ Ahi,
                                       const _Float16* __restrict__ Alo,
                                       const _Float16* __restrict__ B,
                                       int col, int q8, int wv, int lane)
{
    const _Float16* a_h = Ahi + col * KP;
    const _Float16* a_l = Alo + col * KP;
    const int l8 = lane * 8;
    const _Float16* Bw = B + (wv * 4) * 1024 + l8;   // tile (ks,g) at Bw + (g*32+ks)*1024

    f16x8 bh[4], bl[4];
    f16x8 ah0[2], al0[2], ah1[2], al1[2];

    // prologue: A frags for ks=0; B tiles for regions 0..3 (g=0..3 of ks=0)
    ah0[0] = *(const f16x8*)(a_h + q8);
    al0[0] = *(const f16x8*)(a_l + q8);
    ah1[0] = *(const f16x8*)(a_h + 16 * KP + q8);
    al1[0] = *(const f16x8*)(a_l + 16 * KP + q8);
#pragma unroll
    for (int p = 0; p < 4; ++p) {
        const _Float16* pp = Bw + (p * 32) * 1024;   // region p: g=p, ks=0
        bh[p] = *(const f16x8*)(pp);
        bl[p] = *(const f16x8*)(pp + 512);
    }
    __builtin_amdgcn_sched_barrier(0);

#pragma unroll
    for (int it = 0; it < 16; ++it) {
        const int ks = it >> 2, g = it & 3;
        const int sl = it & 3;      // B slot (4-deep)
        const int ka = ks & 1;      // A slot
        __builtin_amdgcn_s_setprio(1);
        acc[0][g] = __builtin_amdgcn_mfma_f32_16x16x32_f16(ah0[ka], bh[sl], acc[0][g], 0, 0, 0);
        acc[0][g] = __builtin_amdgcn_mfma_f32_16x16x32_f16(al0[ka], bh[sl], acc[0][g], 0, 0, 0);
        acc[0][g] = __builtin_amdgcn_mfma_f32_16x16x32_f16(ah0[ka], bl[sl], acc[0][g], 0, 0, 0);
        acc[1][g] = __builtin_amdgcn_mfma_f32_16x16x32_f16(ah1[ka], bh[sl], acc[1][g], 0, 0, 0);
        acc[1][g] = __builtin_amdgcn_mfma_f32_16x16x32_f16(al1[ka], bh[sl], acc[1][g], 0, 0, 0);
        acc[1][g] = __builtin_amdgcn_mfma_f32_16x16x32_f16(ah1[ka], bl[sl], acc[1][g], 0, 0, 0);
        __builtin_amdgcn_s_setprio(0);
        // issue B loads for region it+4 into the just-freed slot
        if (it < 12) {
            const int it4 = it + 4;
            const _Float16* p = Bw + (((it4) & 3) * 32 + ((it4) >> 2)) * 1024;
            bh[sl] = *(const f16x8*)(p);
            bl[sl] = *(const f16x8*)(p + 512);
        }
        // issue A frag loads for ks+1 early in each ks (consumed 4 regions later)
        if (g == 0 && ks < 3) {
            const int ko = (ks + 1) * 32 + q8;
            ah0[ka ^ 1] = *(const f16x8*)(a_h + ko);
            al0[ka ^ 1] = *(const f16x8*)(a_l + ko);
            ah1[ka ^ 1] = *(const f16x8*)(a_h + 16 * KP + ko);
            al1[ka ^ 1] = *(const f16x8*)(a_l + 16 * KP + ko);
        }
        __builtin_amdgcn_sched_barrier(0);   // pin the pipeline: nothing crosses
    }
}

// x-part for layer 0: K=32 (padded), 4 regions, depth-2 B pipeline (1/21 of work)
__device__ __forceinline__ void gemm_x(f32x4 acc[2][4],
                                       const _Float16* __restrict__ Xhi,
                                       const _Float16* __restrict__ Xlo,
                                       const _Float16* __restrict__ B,
                                       int col, int q8, int wv, int lane)
{
    const int l8 = lane * 8;
    const _Float16* Bw = B + wv * 1024 + l8;         // tile g at Bw + g*8*1024
    f16x8 ah0 = *(const f16x8*)(Xhi + col * KP0 + q8);
    f16x8 al0 = *(const f16x8*)(Xlo + col * KP0 + q8);
    f16x8 ah1 = *(const f16x8*)(Xhi + (16 + col) * KP0 + q8);
    f16x8 al1 = *(const f16x8*)(Xlo + (16 + col) * KP0 + q8);
    f16x8 bh[2], bl[2];
    bh[0] = *(const f16x8*)(Bw);
    bl[0] = *(const f16x8*)(Bw + 512);
    bh[1] = *(const f16x8*)(Bw + 8 * 1024);
    bl[1] = *(const f16x8*)(Bw + 8 * 1024 + 512);
    __builtin_amdgcn_sched_barrier(0);
#pragma unroll
    for (int g = 0; g < 4; ++g) {
        const int sl = g & 1;
        __builtin_amdgcn_s_setprio(1);
        acc[0][g] = __builtin_amdgcn_mfma_f32_16x16x32_f16(ah0, bh[sl], acc[0][g], 0, 0, 0);
        acc[0][g] = __builtin_amdgcn_mfma_f32_16x16x32_f16(al0, bh[sl], acc[0][g], 0, 0, 0);
        acc[0][g] = __builtin_amdgcn_mfma_f32_16x16x32_f16(ah0, bl[sl], acc[0][g], 0, 0, 0);
        acc[1][g] = __builtin_amdgcn_mfma_f32_16x16x32_f16(ah1, bh[sl], acc[1][g], 0, 0, 0);
        acc[1][g] = __builtin_amdgcn_mfma_f32_16x16x32_f16(al1, bh[sl], acc[1][g], 0, 0, 0);
        acc[1][g] = __builtin_amdgcn_mfma_f32_16x16x32_f16(ah1, bl[sl], acc[1][g], 0, 0, 0);
        __builtin_amdgcn_s_setprio(0);
        if (g < 2) {
            const _Float16* p = Bw + (g + 2) * 8 * 1024;
            bh[sl] = *(const f16x8*)(p);
            bl[sl] = *(const f16x8*)(p + 512);
        }
        __builtin_amdgcn_sched_barrier(0);
    }
}

// gates + h write for one layer (acc consumed, cst updated, h hi/lo -> LDS)
__device__ __forceinline__ void gates_store(f32x4 acc[2][4], f32x4 cst[2],
                                            _Float16* __restrict__ HsHi,
                                            _Float16* __restrict__ HsLo,
                                            int quad, int col, int wv)
{
#pragma unroll
    for (int mt = 0; mt < 2; ++mt) {
#pragma unroll
        for (int r = 0; r < 4; ++r) {
            float zi = acc[mt][0][r];
            float zf = acc[mt][1][r];
            float zg = acc[mt][2][r];
            float zo = acc[mt][3][r];
            float ig = sigm(zi), fg = sigm(zf), og = sigm(zo), gg = tanh_(zg);
            float cn = fg * cst[mt][r] + ig * gg;
            cst[mt][r] = cn;
            float h = og * tanh_(cn);
            int m = mt * 16 + quad * 4 + r;
            int j = wv * 16 + col;
            _Float16 hh = (_Float16)h;
            HsHi[m * KP + j] = hh;
            HsLo[m * KP + j] = (_Float16)(h - (float)hh);
        }
    }
}

// out[:, t, :] = h2 @ Wl^T + bl (waves 0..3 only: mt = wv>>1, nt = wv&1)
__device__ __forceinline__ void head_out(const _Float16* __restrict__ wsp,
                                         const _Float16* __restrict__ HsHi2,
                                         const _Float16* __restrict__ HsLo2,
                                         float* __restrict__ out, int b0, int t,
                                         int wv, int lane, int col, int quad, int q8,
                                         float blv)
{
    const int mt = wv >> 1, nt = wv & 1;
    const _Float16* ah = HsHi2 + (mt * 16 + col) * KP;
    const _Float16* al = HsLo2 + (mt * 16 + col) * KP;
    f32x4 o = (f32x4){0, 0, 0, 0};
#pragma unroll
    for (int ks = 0; ks < 4; ++ks) {
        const _Float16* bt = wsp + W_HEAD + (nt * 4 + ks) * 1024 + lane * 8;
        f16x8 a_h = *(const f16x8*)(ah + ks * 32 + q8);
        f16x8 a_l = *(const f16x8*)(al + ks * 32 + q8);
        f16x8 b_h = *(const f16x8*)(bt);
        f16x8 b_l = *(const f16x8*)(bt + 512);
        o = __builtin_amdgcn_mfma_f32_16x16x32_f16(a_h, b_h, o, 0, 0, 0);
        o = __builtin_amdgcn_mfma_f32_16x16x32_f16(a_l, b_h, o, 0, 0, 0);
        o = __builtin_amdgcn_mfma_f32_16x16x32_f16(a_h, b_l, o, 0, 0, 0);
    }
    int i = nt * 16 + col;
    if (i < INW) {
#pragma unroll
        for (int r = 0; r < 4; ++r) {
            int m = mt * 16 + quad * 4 + r;
            out[(size_t)(b0 + m) * (TSTEPS * INW) + t * INW + i] = o[r] + blv;
        }
    }
}

// ---------------- main kernel ----------------
// 3-barrier schedule (round 8). Per layer iteration:
//   rec-gemm Whh(l)*h_old(l)  [+ gemm_x / x-loads at l==0; Xs write at l==1; head(t-1) at l==2]
//   BARRIER   (anti-dep: all reads of Hs[l]-old done; visibility: h_new(l-1) published)
//   in-gemm Wih(l)*h_new(l-1)  [l>0]
//   gates(l) -> write Hs[l]
__global__ __launch_bounds__(THREADS, 2) void lstm_mfma(
    const float* __restrict__ x,
    const float* __restrict__ bih0, const float* __restrict__ bhh0,
    const float* __restrict__ bih1, const float* __restrict__ bhh1,
    const float* __restrict__ bih2, const float* __restrict__ bhh2,
    const float* __restrict__ bl,
    const _Float16* __restrict__ wsp,
    float* __restrict__ out)
{
    __shared__ _Float16 Hs[2][3][NROW][KP];    // [hi/lo][layer][m][k]  = 52224 B
    __shared__ _Float16 Xs[2][2][NROW][KP0];   // [buf][hi/lo][m][k]    = 10240 B
    __shared__ float    Bs[3][512];            // bih+bhh per layer     = 6144 B

    const int tid  = threadIdx.x;
    const int wv   = tid >> 6;
    const int lane = tid & 63;
    const int col  = lane & 15;
    const int quad = lane >> 4;
    const int q8   = quad * 8;
    const int b0   = blockIdx.x * NROW;

    // stage bias sums into LDS (saves persistent registers)
    for (int i = tid; i < 1536; i += THREADS) {
        int l = i >> 9, n = i & 511;
        const float* bi = (l == 0) ? bih0 : (l == 1) ? bih1 : bih2;
        const float* bh = (l == 0) ? bhh0 : (l == 1) ? bhh1 : bhh2;
        Bs[l][n] = bi[n] + bh[n];
    }
    // zero h state (hi+lo planes): 52224 B = 13056 floats
    for (int i = tid; i < 13056; i += THREADS) ((float*)Hs)[i] = 0.0f;

    // stage x[:, 0, :] as f16 hi/lo into buffer 0 (K padded to 32)
    for (int ii = tid; ii < NROW * 32; ii += THREADS) {
        int m = ii >> 5, k = ii & 31;
        float v = (k < INW) ? x[(size_t)(b0 + m) * (TSTEPS * INW) + k] : 0.0f;
        _Float16 hi = (_Float16)v;
        Xs[0][0][m][k] = hi;
        Xs[0][1][m][k] = (_Float16)(v - (float)hi);
    }

    f32x4 cst[3][2];
#pragma unroll
    for (int l = 0; l < 3; ++l) { cst[l][0] = (f32x4){0,0,0,0}; cst[l][1] = (f32x4){0,0,0,0}; }

    // weight pointers (fragment-ordered)
    const _Float16* Whh[3] = {wsp + W_BIG,  wsp + W_BIG + 131072, wsp + W_BIG + 262144};
    const _Float16* Wih[3] = {wsp + W_IH0, wsp + W_BIG + 393216, wsp + W_BIG + 524288};

    // head bias (waves 0..3 only)
    float blv = 0.0f;
    {
        int i = (wv & 1) * 16 + col;
        if (wv < 4 && i < INW) blv = bl[i];
    }

    __syncthreads();

    int tb = 0;
#pragma unroll 1
    for (int t = 0; t < TSTEPS; ++t) {
        const int nb = tb ^ 1;
        const int t2 = t + 1;
        float xva[2];

#pragma unroll 1
        for (int l = 0; l < 3; ++l) {
            f32x4 acc[2][4];
#pragma unroll
            for (int mt = 0; mt < 2; ++mt)
#pragma unroll
                for (int g = 0; g < 4; ++g) {
                    float bv = Bs[l][g * 128 + wv * 16 + col];
                    acc[mt][g] = (f32x4){bv, bv, bv, bv};
                }

            if (l == 0) {
                // issue x[t+1] loads early (latency hides under the L0 gemms)
                if (t2 < TSTEPS) {
#pragma unroll
                    for (int u = 0; u < 2; ++u) {
                        int ii = tid + u * THREADS;
                        int m = ii >> 5, k = ii & 31;
                        xva[u] = (k < INW) ? x[(size_t)(b0 + m) * (TSTEPS * INW) + t2 * INW + k] : 0.0f;
                    }
                }
                gemm_x(acc, &Xs[tb][0][0][0], &Xs[tb][1][0][0], Wih[0], col, q8, wv, lane);
            }

            // recurrent contribution (reads Hs[l] OLD)
            gemm_h(acc, &Hs[0][l][0][0], &Hs[1][l][0][0], Whh[l], col, q8, wv, lane);

            if (l == 1 && t2 < TSTEPS) {
                // write x[t+1] to the LDS double-buffer (loads landed during L0/L1 gemms)
#pragma unroll
                for (int u = 0; u < 2; ++u) {
                    int ii = tid + u * THREADS;
                    int m = ii >> 5, k = ii & 31;
                    _Float16 hi = (_Float16)xva[u];
                    Xs[nb][0][m][k] = hi;
                    Xs[nb][1][m][k] = (_Float16)(xva[u] - (float)hi);
                }
            }
            if (l == 2 && t > 0 && wv < 4)
                head_out(wsp, &Hs[0][2][0][0], &Hs[1][2][0][0], out, b0, t - 1,
                         wv, lane, col, quad, q8, blv);

            __syncthreads();   // reads of Hs[l]-old done (all waves); h_new(l-1) visible

            // input contribution (reads Hs[l-1] NEW)
            if (l > 0)
                gemm_h(acc, &Hs[0][l - 1][0][0], &Hs[1][l - 1][0][0], Wih[l], col, q8, wv, lane);

            gates_store(acc, cst[l], &Hs[0][l][0][0], &Hs[1][l][0][0], quad, col, wv);
            // no barrier here: next iteration's rec gemm touches a different Hs buffer
        }

        tb = nb;
    }

    __syncthreads();   // h2(T-1) visible for the epilogue head
    if (wv < 4)
        head_out(wsp, &Hs[0][2][0][0], &Hs[1][2][0][0], out, b0, TSTEPS - 1,
                 wv, lane, col, quad, q8, blv);
}

extern "C" void kernel_launch(void* const* d_in, const int* in_sizes, int n_in,
                              void* d_out, int out_size, void* d_ws, size_t ws_size,
                              hipStream_t stream) {
    const float* x    = (const float*)d_in[0];
    const float* Wih0 = (const float*)d_in[1];
    const float* Whh0 = (const float*)d_in[2];
    const float* bih0 = (const float*)d_in[3];
    const float* bhh0 = (const float*)d_in[4];
    const float* Wih1 = (const float*)d_in[5];
    const float* Whh1 = (const float*)d_in[6];
    const float* bih1 = (const float*)d_in[7];
    const float* bhh1 = (const float*)d_in[8];
    const float* Wih2 = (const float*)d_in[9];
    const float* Whh2 = (const float*)d_in[10];
    const float* bih2 = (const float*)d_in[11];
    const float* bhh2 = (const float*)d_in[12];
    const float* Wl   = (const float*)d_in[13];
    const float* bl   = (const float*)d_in[14];
    float* out = (float*)d_out;
    _Float16* ws = (_Float16*)d_ws;

    convert_w<<<(348160 + 255) / 256, 256, 0, stream>>>(Whh0, Whh1, Whh2, Wih1, Wih2, Wih0, Wl, ws);
    lstm_mfma<<<BATCH / NROW, THREADS, 0, stream>>>(
        x, bih0, bhh0, bih1, bhh1, bih2, bhh2, bl, ws, out);
}

// Round 10
// 563.357 us; speedup vs baseline: 5.4496x; 1.2870x over previous
//
#include <hip/hip_runtime.h>
#include <math.h>

#define BATCH  16384
#define TSTEPS 19
#define INW    17
#define HID    128
#define NROW   32          // batch rows per WG -> grid = 512 = 2 blocks/CU
#define THREADS 512        // 8 waves; wave wv owns j-tile wv (all 4 gates, both m-tiles)
#define KP     136         // padded row length (halfs) for h state (128+8)
#define KP0    40          // padded row length (halfs) for x (32+8)

typedef _Float16 f16x8 __attribute__((ext_vector_type(8)));
typedef float    f32x4 __attribute__((ext_vector_type(4)));

// ---- ws layout (halfs), MFMA-fragment-ordered tiles ----
#define W_BIG      0                 // 5 * 131072 = 655360
#define W_IH0      655360            // [512][32]: n_tile 0..31, tiles of 1024 (hi512|lo512)
#define W_HEAD     688128            // [32 rows][128]: (n_tile 0..1, ks 0..3) tiles of 1024
#define WS_HALFS   696320

__device__ __forceinline__ float fast_rcp(float x) { return __builtin_amdgcn_rcpf(x); }
__device__ __forceinline__ float sigm(float z)  { return fast_rcp(1.0f + __expf(-z)); }
__device__ __forceinline__ float tanh_(float z) { return 1.0f - 2.0f * fast_rcp(1.0f + __expf(2.0f * z)); }

// ---------------- weight conversion: fp32 -> f16 hi/lo, fragment order ----------------
// (lo planes still written; main kernel now consumes hi only + A-side lo for h/x)
__global__ void convert_w(const float* __restrict__ Whh0, const float* __restrict__ Whh1,
                          const float* __restrict__ Whh2, const float* __restrict__ Wih1,
                          const float* __restrict__ Wih2, const float* __restrict__ Wih0,
                          const float* __restrict__ Wl, _Float16* __restrict__ ws)
{
    int idx = blockIdx.x * 256 + threadIdx.x;
    if (idx < 327680) {
        int m = idx >> 16, e = idx & 65535;
        int r = e >> 7, k = e & 127;
        const float* src = (m == 0) ? Whh0 : (m == 1) ? Whh1 : (m == 2) ? Whh2
                          : (m == 3) ? Wih1 : Wih2;
        float v = src[e];
        _Float16 hi = (_Float16)v;
        int n_tile = r >> 4, colr = r & 15, ks = k >> 5, qd = (k >> 3) & 3, j = k & 7;
        int dst = W_BIG + m * 131072 + (n_tile * 4 + ks) * 1024 + (qd * 16 + colr) * 8 + j;
        ws[dst]       = hi;
        ws[dst + 512] = (_Float16)(v - (float)hi);
    } else if (idx < 344064) {
        int e = idx - 327680;              // [0, 16384)
        int r = e >> 5, k = e & 31;
        float v = (k < INW) ? Wih0[r * INW + k] : 0.0f;
        _Float16 hi = (_Float16)v;
        int n_tile = r >> 4, colr = r & 15, qd = k >> 3, j = k & 7;
        int dst = W_IH0 + n_tile * 1024 + (qd * 16 + colr) * 8 + j;
        ws[dst]       = hi;
        ws[dst + 512] = (_Float16)(v - (float)hi);
    } else if (idx < 348160) {
        int e = idx - 344064;              // [0, 4096)
        int r = e >> 7, k = e & 127;
        float v = (r < INW) ? Wl[(size_t)r * HID + k] : 0.0f;
        _Float16 hi = (_Float16)v;
        int n_tile = r >> 4, colr = r & 15, ks = k >> 5, qd = (k >> 3) & 3, j = k & 7;
        int dst = W_HEAD + (n_tile * 4 + ks) * 1024 + (qd * 16 + colr) * 8 + j;
        ws[dst]       = hi;
        ws[dst + 512] = (_Float16)(v - (float)hi);
    }
}

// ---------------- GEMM helpers (software-pipelined, sched_barrier-fenced) ----------------
// acc[mt][g]: rows m = mt*16 + quad*4 + r, cols n = g*128 + wv*16 + col
// A from LDS h planes (hi/lo, row-major stride KP); B fragment tiles (coalesced lane*8).
// 2-term emulation: z = A_hi*B_hi + A_lo*B_hi (B-lo correction dropped: ~5e-5 z error,
// 20x below measured absmax; -33% MFMA count, -50% B-load bytes).
// Pipeline: B tiles 4-slot (issued 4 regions ahead ~= L2 latency); A frags dbuf per ks.
__device__ __forceinline__ void gemm_h(f32x4 acc[2][4],
                                       const _Float16* __restrict__ Ahi,
                                       const _Float16* __restrict__ Alo,
                                       const _Float16* __restrict__ B,
                                       int col, int q8, int wv, int lane)
{
    const _Float16* a_h = Ahi + col * KP;
    const _Float16* a_l = Alo + col * KP;
    const int l8 = lane * 8;
    const _Float16* Bw = B + (wv * 4) * 1024 + l8;   // tile (ks,g) at Bw + (g*32+ks)*1024

    f16x8 bh[4];
    f16x8 ah0[2], al0[2], ah1[2], al1[2];

    // prologue: A frags for ks=0; B tiles for regions 0..3 (g=0..3 of ks=0)
    ah0[0] = *(const f16x8*)(a_h + q8);
    al0[0] = *(const f16x8*)(a_l + q8);
    ah1[0] = *(const f16x8*)(a_h + 16 * KP + q8);
    al1[0] = *(const f16x8*)(a_l + 16 * KP + q8);
#pragma unroll
    for (int p = 0; p < 4; ++p)
        bh[p] = *(const f16x8*)(Bw + (p * 32) * 1024);   // region p: g=p, ks=0
    __builtin_amdgcn_sched_barrier(0);

#pragma unroll
    for (int it = 0; it < 16; ++it) {
        const int ks = it >> 2, g = it & 3;
        const int sl = it & 3;      // B slot (4-deep)
        const int ka = ks & 1;      // A slot
        __builtin_amdgcn_s_setprio(1);
        acc[0][g] = __builtin_amdgcn_mfma_f32_16x16x32_f16(ah0[ka], bh[sl], acc[0][g], 0, 0, 0);
        acc[0][g] = __builtin_amdgcn_mfma_f32_16x16x32_f16(al0[ka], bh[sl], acc[0][g], 0, 0, 0);
        acc[1][g] = __builtin_amdgcn_mfma_f32_16x16x32_f16(ah1[ka], bh[sl], acc[1][g], 0, 0, 0);
        acc[1][g] = __builtin_amdgcn_mfma_f32_16x16x32_f16(al1[ka], bh[sl], acc[1][g], 0, 0, 0);
        __builtin_amdgcn_s_setprio(0);
        // issue B load for region it+4 into the just-freed slot
        if (it < 12) {
            const int it4 = it + 4;
            bh[sl] = *(const f16x8*)(Bw + (((it4) & 3) * 32 + ((it4) >> 2)) * 1024);
        }
        // issue A frag loads for ks+1 early in each ks (consumed 4 regions later)
        if (g == 0 && ks < 3) {
            const int ko = (ks + 1) * 32 + q8;
            ah0[ka ^ 1] = *(const f16x8*)(a_h + ko);
            al0[ka ^ 1] = *(const f16x8*)(a_l + ko);
            ah1[ka ^ 1] = *(const f16x8*)(a_h + 16 * KP + ko);
            al1[ka ^ 1] = *(const f16x8*)(a_l + 16 * KP + ko);
        }
        __builtin_amdgcn_sched_barrier(0);   // pin the pipeline: nothing crosses
    }
}

// x-part for layer 0: K=32 (padded), 4 regions, depth-2 B pipeline (1/21 of work)
__device__ __forceinline__ void gemm_x(f32x4 acc[2][4],
                                       const _Float16* __restrict__ Xhi,
                                       const _Float16* __restrict__ Xlo,
                                       const _Float16* __restrict__ B,
                                       int col, int q8, int wv, int lane)
{
    const int l8 = lane * 8;
    const _Float16* Bw = B + wv * 1024 + l8;         // tile g at Bw + g*8*1024
    f16x8 ah0 = *(const f16x8*)(Xhi + col * KP0 + q8);
    f16x8 al0 = *(const f16x8*)(Xlo + col * KP0 + q8);
    f16x8 ah1 = *(const f16x8*)(Xhi + (16 + col) * KP0 + q8);
    f16x8 al1 = *(const f16x8*)(Xlo + (16 + col) * KP0 + q8);
    f16x8 bh[2];
    bh[0] = *(const f16x8*)(Bw);
    bh[1] = *(const f16x8*)(Bw + 8 * 1024);
    __builtin_amdgcn_sched_barrier(0);
#pragma unroll
    for (int g = 0; g < 4; ++g) {
        const int sl = g & 1;
        __builtin_amdgcn_s_setprio(1);
        acc[0][g] = __builtin_amdgcn_mfma_f32_16x16x32_f16(ah0, bh[sl], acc[0][g], 0, 0, 0);
        acc[0][g] = __builtin_amdgcn_mfma_f32_16x16x32_f16(al0, bh[sl], acc[0][g], 0, 0, 0);
        acc[1][g] = __builtin_amdgcn_mfma_f32_16x16x32_f16(ah1, bh[sl], acc[1][g], 0, 0, 0);
        acc[1][g] = __builtin_amdgcn_mfma_f32_16x16x32_f16(al1, bh[sl], acc[1][g], 0, 0, 0);
        __builtin_amdgcn_s_setprio(0);
        if (g < 2)
            bh[sl] = *(const f16x8*)(Bw + (g + 2) * 8 * 1024);
        __builtin_amdgcn_sched_barrier(0);
    }
}

// gates + h write for one layer (acc consumed, cst updated, h hi/lo -> LDS)
__device__ __forceinline__ void gates_store(f32x4 acc[2][4], f32x4 cst[2],
                                            _Float16* __restrict__ HsHi,
                                            _Float16* __restrict__ HsLo,
                                            int quad, int col, int wv)
{
#pragma unroll
    for (int mt = 0; mt < 2; ++mt) {
#pragma unroll
        for (int r = 0; r < 4; ++r) {
            float zi = acc[mt][0][r];
            float zf = acc[mt][1][r];
            float zg = acc[mt][2][r];
            float zo = acc[mt][3][r];
            float ig = sigm(zi), fg = sigm(zf), og = sigm(zo), gg = tanh_(zg);
            float cn = fg * cst[mt][r] + ig * gg;
            cst[mt][r] = cn;
            float h = og * tanh_(cn);
            int m = mt * 16 + quad * 4 + r;
            int j = wv * 16 + col;
            _Float16 hh = (_Float16)h;
            HsHi[m * KP + j] = hh;
            HsLo[m * KP + j] = (_Float16)(h - (float)hh);
        }
    }
}

// out[:, t, :] = h2 @ Wl^T + bl (waves 0..3 only: mt = wv>>1, nt = wv&1)
__device__ __forceinline__ void head_out(const _Float16* __restrict__ wsp,
                                         const _Float16* __restrict__ HsHi2,
                                         const _Float16* __restrict__ HsLo2,
                                         float* __restrict__ out, int b0, int t,
                                         int wv, int lane, int col, int quad, int q8,
                                         float blv)
{
    const int mt = wv >> 1, nt = wv & 1;
    const _Float16* ah = HsHi2 + (mt * 16 + col) * KP;
    const _Float16* al = HsLo2 + (mt * 16 + col) * KP;
    f32x4 o = (f32x4){0, 0, 0, 0};
#pragma unroll
    for (int ks = 0; ks < 4; ++ks) {
        const _Float16* bt = wsp + W_HEAD + (nt * 4 + ks) * 1024 + lane * 8;
        f16x8 a_h = *(const f16x8*)(ah + ks * 32 + q8);
        f16x8 a_l = *(const f16x8*)(al + ks * 32 + q8);
        f16x8 b_h = *(const f16x8*)(bt);
        o = __builtin_amdgcn_mfma_f32_16x16x32_f16(a_h, b_h, o, 0, 0, 0);
        o = __builtin_amdgcn_mfma_f32_16x16x32_f16(a_l, b_h, o, 0, 0, 0);
    }
    int i = nt * 16 + col;
    if (i < INW) {
#pragma unroll
        for (int r = 0; r < 4; ++r) {
            int m = mt * 16 + quad * 4 + r;
            out[(size_t)(b0 + m) * (TSTEPS * INW) + t * INW + i] = o[r] + blv;
        }
    }
}

// ---------------- main kernel ----------------
// 3-barrier schedule (round 8). Per layer iteration:
//   rec-gemm Whh(l)*h_old(l)  [+ gemm_x / x-loads at l==0; Xs write at l==1; head(t-1) at l==2]
//   BARRIER   (anti-dep: all reads of Hs[l]-old done; visibility: h_new(l-1) published)
//   in-gemm Wih(l)*h_new(l-1)  [l>0]
//   gates(l) -> write Hs[l]
__global__ __launch_bounds__(THREADS, 2) void lstm_mfma(
    const float* __restrict__ x,
    const float* __restrict__ bih0, const float* __restrict__ bhh0,
    const float* __restrict__ bih1, const float* __restrict__ bhh1,
    const float* __restrict__ bih2, const float* __restrict__ bhh2,
    const float* __restrict__ bl,
    const _Float16* __restrict__ wsp,
    float* __restrict__ out)
{
    __shared__ _Float16 Hs[2][3][NROW][KP];    // [hi/lo][layer][m][k]  = 52224 B
    __shared__ _Float16 Xs[2][2][NROW][KP0];   // [buf][hi/lo][m][k]    = 10240 B
    __shared__ float    Bs[3][512];            // bih+bhh per layer     = 6144 B

    const int tid  = threadIdx.x;
    const int wv   = tid >> 6;
    const int lane = tid & 63;
    const int col  = lane & 15;
    const int quad = lane >> 4;
    const int q8   = quad * 8;
    const int b0   = blockIdx.x * NROW;

    // stage bias sums into LDS (saves persistent registers)
    for (int i = tid; i < 1536; i += THREADS) {
        int l = i >> 9, n = i & 511;
        const float* bi = (l == 0) ? bih0 : (l == 1) ? bih1 : bih2;
        const float* bh = (l == 0) ? bhh0 : (l == 1) ? bhh1 : bhh2;
        Bs[l][n] = bi[n] + bh[n];
    }
    // zero h state (hi+lo planes): 52224 B = 13056 floats
    for (int i = tid; i < 13056; i += THREADS) ((float*)Hs)[i] = 0.0f;

    // stage x[:, 0, :] as f16 hi/lo into buffer 0 (K padded to 32)
    for (int ii = tid; ii < NROW * 32; ii += THREADS) {
        int m = ii >> 5, k = ii & 31;
        float v = (k < INW) ? x[(size_t)(b0 + m) * (TSTEPS * INW) + k] : 0.0f;
        _Float16 hi = (_Float16)v;
        Xs[0][0][m][k] = hi;
        Xs[0][1][m][k] = (_Float16)(v - (float)hi);
    }

    f32x4 cst[3][2];
#pragma unroll
    for (int l = 0; l < 3; ++l) { cst[l][0] = (f32x4){0,0,0,0}; cst[l][1] = (f32x4){0,0,0,0}; }

    // weight pointers (fragment-ordered)
    const _Float16* Whh[3] = {wsp + W_BIG,  wsp + W_BIG + 131072, wsp + W_BIG + 262144};
    const _Float16* Wih[3] = {wsp + W_IH0, wsp + W_BIG + 393216, wsp + W_BIG + 524288};

    // head bias (waves 0..3 only)
    float blv = 0.0f;
    {
        int i = (wv & 1) * 16 + col;
        if (wv < 4 && i < INW) blv = bl[i];
    }

    __syncthreads();

    int tb = 0;
#pragma unroll 1
    for (int t = 0; t < TSTEPS; ++t) {
        const int nb = tb ^ 1;
        const int t2 = t + 1;
        float xva[2];

#pragma unroll 1
        for (int l = 0; l < 3; ++l) {
            f32x4 acc[2][4];
#pragma unroll
            for (int mt = 0; mt < 2; ++mt)
#pragma unroll
                for (int g = 0; g < 4; ++g) {
                    float bv = Bs[l][g * 128 + wv * 16 + col];
                    acc[mt][g] = (f32x4){bv, bv, bv, bv};
                }

            if (l == 0) {
                // issue x[t+1] loads early (latency hides under the L0 gemms)
                if (t2 < TSTEPS) {
#pragma unroll
                    for (int u = 0; u < 2; ++u) {
                        int ii = tid + u * THREADS;
                        int m = ii >> 5, k = ii & 31;
                        xva[u] = (k < INW) ? x[(size_t)(b0 + m) * (TSTEPS * INW) + t2 * INW + k] : 0.0f;
                    }
                }
                gemm_x(acc, &Xs[tb][0][0][0], &Xs[tb][1][0][0], Wih[0], col, q8, wv, lane);
            }

            // recurrent contribution (reads Hs[l] OLD)
            gemm_h(acc, &Hs[0][l][0][0], &Hs[1][l][0][0], Whh[l], col, q8, wv, lane);

            if (l == 1 && t2 < TSTEPS) {
                // write x[t+1] to the LDS double-buffer (loads landed during L0/L1 gemms)
#pragma unroll
                for (int u = 0; u < 2; ++u) {
                    int ii = tid + u * THREADS;
                    int m = ii >> 5, k = ii & 31;
                    _Float16 hi = (_Float16)xva[u];
                    Xs[nb][0][m][k] = hi;
                    Xs[nb][1][m][k] = (_Float16)(xva[u] - (float)hi);
                }
            }
            if (l == 2 && t > 0 && wv < 4)
                head_out(wsp, &Hs[0][2][0][0], &Hs[1][2][0][0], out, b0, t - 1,
                         wv, lane, col, quad, q8, blv);

            __syncthreads();   // reads of Hs[l]-old done (all waves); h_new(l-1) visible

            // input contribution (reads Hs[l-1] NEW)
            if (l > 0)
                gemm_h(acc, &Hs[0][l - 1][0][0], &Hs[1][l - 1][0][0], Wih[l], col, q8, wv, lane);

            gates_store(acc, cst[l], &Hs[0][l][0][0], &Hs[1][l][0][0], quad, col, wv);
            // no barrier here: next iteration's rec gemm touches a different Hs buffer
        }

        tb = nb;
    }

    __syncthreads();   // h2(T-1) visible for the epilogue head
    if (wv < 4)
        head_out(wsp, &Hs[0][2][0][0], &Hs[1][2][0][0], out, b0, TSTEPS - 1,
                 wv, lane, col, quad, q8, blv);
}

extern "C" void kernel_launch(void* const* d_in, const int* in_sizes, int n_in,
                              void* d_out, int out_size, void* d_ws, size_t ws_size,
                              hipStream_t stream) {
    const float* x    = (const float*)d_in[0];
    const float* Wih0 = (const float*)d_in[1];
    const float* Whh0 = (const float*)d_in[2];
    const float* bih0 = (const float*)d_in[3];
    const float* bhh0 = (const float*)d_in[4];
    const float* Wih1 = (const float*)d_in[5];
    const float* Whh1 = (const float*)d_in[6];
    const float* bih1 = (const float*)d_in[7];
    const float* bhh1 = (const float*)d_in[8];
    const float* Wih2 = (const float*)d_in[9];
    const float* Whh2 = (const float*)d_in[10];
    const float* bih2 = (const float*)d_in[11];
    const float* bhh2 = (const float*)d_in[12];
    const float* Wl   = (const float*)d_in[13];
    const float* bl   = (const float*)d_in[14];
    float* out = (float*)d_out;
    _Float16* ws = (_Float16*)d_ws;

    convert_w<<<(348160 + 255) / 256, 256, 0, stream>>>(Whh0, Whh1, Whh2, Wih1, Wih2, Wih0, Wl, ws);
    lstm_mfma<<<BATCH / NROW, THREADS, 0, stream>>>(
        x, bih0, bhh0, bih1, bhh1, bih2, bhh2, bl, ws, out);
}

// Round 11
// 473.926 us; speedup vs baseline: 6.4780x; 1.1887x over previous
//
#include <hip/hip_runtime.h>
#include <math.h>

#define BATCH  16384
#define TSTEPS 19
#define INW    17
#define HID    128
#define NROW   32          // batch rows per WG -> grid = 512 = 2 blocks/CU
#define THREADS 512        // 8 waves; wave wv owns j-tile wv (all 4 gates, both m-tiles)
#define KP     136         // padded row length (halfs) for h state (128+8)
#define KP0    40          // padded row length (halfs) for x (32+8)

typedef _Float16 f16x8 __attribute__((ext_vector_type(8)));
typedef float    f32x4 __attribute__((ext_vector_type(4)));

// ---- ws layout (halfs), MFMA-fragment-ordered tiles ----
#define W_BIG      0                 // 5 * 131072 = 655360
#define W_IH0      655360            // [512][32]: n_tile 0..31, tiles of 1024 (hi512|lo512)
#define W_HEAD     688128            // [32 rows][128]: (n_tile 0..1, ks 0..3) tiles of 1024
#define WS_HALFS   696320

__device__ __forceinline__ float fast_rcp(float x) { return __builtin_amdgcn_rcpf(x); }
__device__ __forceinline__ float sigm(float z)  { return fast_rcp(1.0f + __expf(-z)); }
__device__ __forceinline__ float tanh_(float z) { return 1.0f - 2.0f * fast_rcp(1.0f + __expf(2.0f * z)); }

// ---------------- weight conversion: fp32 -> f16 hi (lo planes written but unused) ----------------
__global__ void convert_w(const float* __restrict__ Whh0, const float* __restrict__ Whh1,
                          const float* __restrict__ Whh2, const float* __restrict__ Wih1,
                          const float* __restrict__ Wih2, const float* __restrict__ Wih0,
                          const float* __restrict__ Wl, _Float16* __restrict__ ws)
{
    int idx = blockIdx.x * 256 + threadIdx.x;
    if (idx < 327680) {
        int m = idx >> 16, e = idx & 65535;
        int r = e >> 7, k = e & 127;
        const float* src = (m == 0) ? Whh0 : (m == 1) ? Whh1 : (m == 2) ? Whh2
                          : (m == 3) ? Wih1 : Wih2;
        float v = src[e];
        _Float16 hi = (_Float16)v;
        int n_tile = r >> 4, colr = r & 15, ks = k >> 5, qd = (k >> 3) & 3, j = k & 7;
        int dst = W_BIG + m * 131072 + (n_tile * 4 + ks) * 1024 + (qd * 16 + colr) * 8 + j;
        ws[dst]       = hi;
        ws[dst + 512] = (_Float16)(v - (float)hi);
    } else if (idx < 344064) {
        int e = idx - 327680;              // [0, 16384)
        int r = e >> 5, k = e & 31;
        float v = (k < INW) ? Wih0[r * INW + k] : 0.0f;
        _Float16 hi = (_Float16)v;
        int n_tile = r >> 4, colr = r & 15, qd = k >> 3, j = k & 7;
        int dst = W_IH0 + n_tile * 1024 + (qd * 16 + colr) * 8 + j;
        ws[dst]       = hi;
        ws[dst + 512] = (_Float16)(v - (float)hi);
    } else if (idx < 348160) {
        int e = idx - 344064;              // [0, 4096)
        int r = e >> 7, k = e & 127;
        float v = (r < INW) ? Wl[(size_t)r * HID + k] : 0.0f;
        _Float16 hi = (_Float16)v;
        int n_tile = r >> 4, colr = r & 15, ks = k >> 5, qd = (k >> 3) & 3, j = k & 7;
        int dst = W_HEAD + (n_tile * 4 + ks) * 1024 + (qd * 16 + colr) * 8 + j;
        ws[dst]       = hi;
        ws[dst + 512] = (_Float16)(v - (float)hi);
    }
}

// ---------------- GEMM helpers (software-pipelined, sched_barrier-fenced) ----------------
// acc[mt][g]: rows m = mt*16 + quad*4 + r, cols n = g*128 + wv*16 + col
// Pure-f16 gemm: z = A_hi*B_hi (both lo corrections dropped; each was ~5e-5 z-noise,
// 20x below measured absmax; round 10 proved B-lo drop was bit-neutral on output).
// A from LDS h plane (row-major stride KP); B fragment tiles (coalesced lane*8).
// Pipeline: B tiles 4-slot (issued 4 regions ahead ~= L2 latency); A frags dbuf per ks.
__device__ __forceinline__ void gemm_h(f32x4 acc[2][4],
                                       const _Float16* __restrict__ A,
                                       const _Float16* __restrict__ B,
                                       int col, int q8, int wv, int lane)
{
    const _Float16* a_p = A + col * KP;
    const int l8 = lane * 8;
    const _Float16* Bw = B + (wv * 4) * 1024 + l8;   // tile (ks,g) at Bw + (g*32+ks)*1024

    f16x8 bh[4];
    f16x8 ah0[2], ah1[2];

    // prologue: A frags for ks=0; B tiles for regions 0..3 (g=0..3 of ks=0)
    ah0[0] = *(const f16x8*)(a_p + q8);
    ah1[0] = *(const f16x8*)(a_p + 16 * KP + q8);
#pragma unroll
    for (int p = 0; p < 4; ++p)
        bh[p] = *(const f16x8*)(Bw + (p * 32) * 1024);   // region p: g=p, ks=0
    __builtin_amdgcn_sched_barrier(0);

#pragma unroll
    for (int it = 0; it < 16; ++it) {
        const int ks = it >> 2, g = it & 3;
        const int sl = it & 3;      // B slot (4-deep)
        const int ka = ks & 1;      // A slot
        __builtin_amdgcn_s_setprio(1);
        acc[0][g] = __builtin_amdgcn_mfma_f32_16x16x32_f16(ah0[ka], bh[sl], acc[0][g], 0, 0, 0);
        acc[1][g] = __builtin_amdgcn_mfma_f32_16x16x32_f16(ah1[ka], bh[sl], acc[1][g], 0, 0, 0);
        __builtin_amdgcn_s_setprio(0);
        // issue B load for region it+4 into the just-freed slot
        if (it < 12) {
            const int it4 = it + 4;
            bh[sl] = *(const f16x8*)(Bw + (((it4) & 3) * 32 + ((it4) >> 2)) * 1024);
        }
        // issue A frag loads for ks+1 early in each ks (consumed 4 regions later)
        if (g == 0 && ks < 3) {
            const int ko = (ks + 1) * 32 + q8;
            ah0[ka ^ 1] = *(const f16x8*)(a_p + ko);
            ah1[ka ^ 1] = *(const f16x8*)(a_p + 16 * KP + ko);
        }
        __builtin_amdgcn_sched_barrier(0);   // pin the pipeline: nothing crosses
    }
}

// x-part for layer 0: K=32 (padded), 4 regions, depth-2 B pipeline (1/21 of work)
__device__ __forceinline__ void gemm_x(f32x4 acc[2][4],
                                       const _Float16* __restrict__ X,
                                       const _Float16* __restrict__ B,
                                       int col, int q8, int wv, int lane)
{
    const int l8 = lane * 8;
    const _Float16* Bw = B + wv * 1024 + l8;         // tile g at Bw + g*8*1024
    f16x8 ah0 = *(const f16x8*)(X + col * KP0 + q8);
    f16x8 ah1 = *(const f16x8*)(X + (16 + col) * KP0 + q8);
    f16x8 bh[2];
    bh[0] = *(const f16x8*)(Bw);
    bh[1] = *(const f16x8*)(Bw + 8 * 1024);
    __builtin_amdgcn_sched_barrier(0);
#pragma unroll
    for (int g = 0; g < 4; ++g) {
        const int sl = g & 1;
        __builtin_amdgcn_s_setprio(1);
        acc[0][g] = __builtin_amdgcn_mfma_f32_16x16x32_f16(ah0, bh[sl], acc[0][g], 0, 0, 0);
        acc[1][g] = __builtin_amdgcn_mfma_f32_16x16x32_f16(ah1, bh[sl], acc[1][g], 0, 0, 0);
        __builtin_amdgcn_s_setprio(0);
        if (g < 2)
            bh[sl] = *(const f16x8*)(Bw + (g + 2) * 8 * 1024);
        __builtin_amdgcn_sched_barrier(0);
    }
}

// gates + h write for one layer (acc consumed, cst updated, h f16 -> LDS)
__device__ __forceinline__ void gates_store(f32x4 acc[2][4], f32x4 cst[2],
                                            _Float16* __restrict__ HsP,
                                            int quad, int col, int wv)
{
#pragma unroll
    for (int mt = 0; mt < 2; ++mt) {
#pragma unroll
        for (int r = 0; r < 4; ++r) {
            float zi = acc[mt][0][r];
            float zf = acc[mt][1][r];
            float zg = acc[mt][2][r];
            float zo = acc[mt][3][r];
            float ig = sigm(zi), fg = sigm(zf), og = sigm(zo), gg = tanh_(zg);
            float cn = fg * cst[mt][r] + ig * gg;
            cst[mt][r] = cn;
            float h = og * tanh_(cn);
            int m = mt * 16 + quad * 4 + r;
            int j = wv * 16 + col;
            HsP[m * KP + j] = (_Float16)h;
        }
    }
}

// out[:, t, :] = h2 @ Wl^T + bl (waves 0..3 only: mt = wv>>1, nt = wv&1)
__device__ __forceinline__ void head_out(const _Float16* __restrict__ wsp,
                                         const _Float16* __restrict__ Hs2,
                                         float* __restrict__ out, int b0, int t,
                                         int wv, int lane, int col, int quad, int q8,
                                         float blv)
{
    const int mt = wv >> 1, nt = wv & 1;
    const _Float16* ah = Hs2 + (mt * 16 + col) * KP;
    f32x4 o = (f32x4){0, 0, 0, 0};
#pragma unroll
    for (int ks = 0; ks < 4; ++ks) {
        const _Float16* bt = wsp + W_HEAD + (nt * 4 + ks) * 1024 + lane * 8;
        f16x8 a_h = *(const f16x8*)(ah + ks * 32 + q8);
        f16x8 b_h = *(const f16x8*)(bt);
        o = __builtin_amdgcn_mfma_f32_16x16x32_f16(a_h, b_h, o, 0, 0, 0);
    }
    int i = nt * 16 + col;
    if (i < INW) {
#pragma unroll
        for (int r = 0; r < 4; ++r) {
            int m = mt * 16 + quad * 4 + r;
            out[(size_t)(b0 + m) * (TSTEPS * INW) + t * INW + i] = o[r] + blv;
        }
    }
}

// ---------------- main kernel ----------------
// 3-barrier schedule (round 8). Per layer iteration:
//   rec-gemm Whh(l)*h_old(l)  [+ gemm_x / x-loads at l==0; Xs write at l==1; head(t-1) at l==2]
//   BARRIER   (anti-dep: all reads of Hs[l]-old done; visibility: h_new(l-1) published)
//   in-gemm Wih(l)*h_new(l-1)  [l>0]
//   gates(l) -> write Hs[l]
__global__ __launch_bounds__(THREADS, 2) void lstm_mfma(
    const float* __restrict__ x,
    const float* __restrict__ bih0, const float* __restrict__ bhh0,
    const float* __restrict__ bih1, const float* __restrict__ bhh1,
    const float* __restrict__ bih2, const float* __restrict__ bhh2,
    const float* __restrict__ bl,
    const _Float16* __restrict__ wsp,
    float* __restrict__ out)
{
    __shared__ _Float16 Hs[3][NROW][KP];      // [layer][m][k]  = 26112 B
    __shared__ _Float16 Xs[2][NROW][KP0];     // [buf][m][k]    = 5120 B
    __shared__ float    Bs[3][512];           // bih+bhh/layer  = 6144 B

    const int tid  = threadIdx.x;
    const int wv   = tid >> 6;
    const int lane = tid & 63;
    const int col  = lane & 15;
    const int quad = lane >> 4;
    const int q8   = quad * 8;
    const int b0   = blockIdx.x * NROW;

    // stage bias sums into LDS (saves persistent registers)
    for (int i = tid; i < 1536; i += THREADS) {
        int l = i >> 9, n = i & 511;
        const float* bi = (l == 0) ? bih0 : (l == 1) ? bih1 : bih2;
        const float* bh = (l == 0) ? bhh0 : (l == 1) ? bhh1 : bhh2;
        Bs[l][n] = bi[n] + bh[n];
    }
    // zero h state: 26112 B = 6528 floats
    for (int i = tid; i < 6528; i += THREADS) ((float*)Hs)[i] = 0.0f;

    // stage x[:, 0, :] as f16 into buffer 0 (K padded to 32)
    for (int ii = tid; ii < NROW * 32; ii += THREADS) {
        int m = ii >> 5, k = ii & 31;
        float v = (k < INW) ? x[(size_t)(b0 + m) * (TSTEPS * INW) + k] : 0.0f;
        Xs[0][m][k] = (_Float16)v;
    }

    f32x4 cst[3][2];
#pragma unroll
    for (int l = 0; l < 3; ++l) { cst[l][0] = (f32x4){0,0,0,0}; cst[l][1] = (f32x4){0,0,0,0}; }

    // weight pointers (fragment-ordered)
    const _Float16* Whh[3] = {wsp + W_BIG,  wsp + W_BIG + 131072, wsp + W_BIG + 262144};
    const _Float16* Wih[3] = {wsp + W_IH0, wsp + W_BIG + 393216, wsp + W_BIG + 524288};

    // head bias (waves 0..3 only)
    float blv = 0.0f;
    {
        int i = (wv & 1) * 16 + col;
        if (wv < 4 && i < INW) blv = bl[i];
    }

    __syncthreads();

    int tb = 0;
#pragma unroll 1
    for (int t = 0; t < TSTEPS; ++t) {
        const int nb = tb ^ 1;
        const int t2 = t + 1;
        float xva[2];

#pragma unroll 1
        for (int l = 0; l < 3; ++l) {
            f32x4 acc[2][4];
#pragma unroll
            for (int mt = 0; mt < 2; ++mt)
#pragma unroll
                for (int g = 0; g < 4; ++g) {
                    float bv = Bs[l][g * 128 + wv * 16 + col];
                    acc[mt][g] = (f32x4){bv, bv, bv, bv};
                }

            if (l == 0) {
                // issue x[t+1] loads early (latency hides under the L0 gemms)
                if (t2 < TSTEPS) {
#pragma unroll
                    for (int u = 0; u < 2; ++u) {
                        int ii = tid + u * THREADS;
                        int m = ii >> 5, k = ii & 31;
                        xva[u] = (k < INW) ? x[(size_t)(b0 + m) * (TSTEPS * INW) + t2 * INW + k] : 0.0f;
                    }
                }
                gemm_x(acc, &Xs[tb][0][0], Wih[0], col, q8, wv, lane);
            }

            // recurrent contribution (reads Hs[l] OLD)
            gemm_h(acc, &Hs[l][0][0], Whh[l], col, q8, wv, lane);

            if (l == 1 && t2 < TSTEPS) {
                // write x[t+1] to the LDS double-buffer (loads landed during L0/L1 gemms)
#pragma unroll
                for (int u = 0; u < 2; ++u) {
                    int ii = tid + u * THREADS;
                    int m = ii >> 5, k = ii & 31;
                    Xs[nb][m][k] = (_Float16)xva[u];
                }
            }
            if (l == 2 && t > 0 && wv < 4)
                head_out(wsp, &Hs[2][0][0], out, b0, t - 1,
                         wv, lane, col, quad, q8, blv);

            __syncthreads();   // reads of Hs[l]-old done (all waves); h_new(l-1) visible

            // input contribution (reads Hs[l-1] NEW)
            if (l > 0)
                gemm_h(acc, &Hs[l - 1][0][0], Wih[l], col, q8, wv, lane);

            gates_store(acc, cst[l], &Hs[l][0][0], quad, col, wv);
            // no barrier here: next iteration's rec gemm touches a different Hs buffer
        }

        tb = nb;
    }

    __syncthreads();   // h2(T-1) visible for the epilogue head
    if (wv < 4)
        head_out(wsp, &Hs[2][0][0], out, b0, TSTEPS - 1,
                 wv, lane, col, quad, q8, blv);
}

extern "C" void kernel_launch(void* const* d_in, const int* in_sizes, int n_in,
                              void* d_out, int out_size, void* d_ws, size_t ws_size,
                              hipStream_t stream) {
    const float* x    = (const float*)d_in[0];
    const float* Wih0 = (const float*)d_in[1];
    const float* Whh0 = (const float*)d_in[2];
    const float* bih0 = (const float*)d_in[3];
    const float* bhh0 = (const float*)d_in[4];
    const float* Wih1 = (const float*)d_in[5];
    const float* Whh1 = (const float*)d_in[6];
    const float* bih1 = (const float*)d_in[7];
    const float* bhh1 = (const float*)d_in[8];
    const float* Wih2 = (const float*)d_in[9];
    const float* Whh2 = (const float*)d_in[10];
    const float* bih2 = (const float*)d_in[11];
    const float* bhh2 = (const float*)d_in[12];
    const float* Wl   = (const float*)d_in[13];
    const float* bl   = (const float*)d_in[14];
    float* out = (float*)d_out;
    _Float16* ws = (_Float16*)d_ws;

    convert_w<<<(348160 + 255) / 256, 256, 0, stream>>>(Whh0, Whh1, Whh2, Wih1, Wih2, Wih0, Wl, ws);
    lstm_mfma<<<BATCH / NROW, THREADS, 0, stream>>>(
        x, bih0, bhh0, bih1, bhh1, bih2, bhh2, bl, ws, out);
}